// Round 11
// baseline (464.112 us; speedup 1.0000x reference)
//
#include <hip/hip_runtime.h>
#include <stdint.h>

// Problem dims
#define T_TOT 32768   // B*S
#define H_DIM 1024
#define A_DIM 32
#define E_NUM 8
#define ED_DIM 256
#define RH_DIM 128
#define NBIG 2560     // 8*256 experts + 256 shared + 128 router + 128 value
#define K2 2304       // 8*256 + 256 (expert+shared h1 -> action)

typedef float f32x4 __attribute__((ext_vector_type(4)));
typedef short bf16x8 __attribute__((ext_vector_type(8)));
typedef unsigned short u16;
typedef u16 u16x8 __attribute__((ext_vector_type(8)));

typedef uint32_t __attribute__((address_space(1))) as1_u32;
typedef uint32_t __attribute__((address_space(3))) as3_u32;

__device__ __forceinline__ u16 f2bf(float f) {
    union { float f; uint32_t u; } v; v.f = f;
    return (u16)((v.u + 0x7FFFu + ((v.u >> 16) & 1u)) >> 16);  // RNE
}
__device__ __forceinline__ float bf2f(u16 h) {
    union { uint32_t u; float f; } v; v.u = ((uint32_t)h) << 16;
    return v.f;
}
// tanh-form GELU: x * sigmoid(1.5957691*x*(1+0.044715 x^2)).
// 8 VALU ops vs 16 for the A&S erf form; |diff vs erf-gelu| <= ~3e-3 << 0.121.
// Large |x| safe: exp(-s)->0 => x; exp(+s)->inf => rcp -> 0.
__device__ __forceinline__ float gelu_fast(float x) {
    const float x2 = x * x;
    const float s = x * fmaf(0.07135481627f, x2, 1.5957691216f);  // 2z
    const float e = __expf(-s);
    return x * __builtin_amdgcn_rcpf(1.0f + e);
}
__device__ __forceinline__ void gload_lds16(const void* g, void* lds) {
    __builtin_amdgcn_global_load_lds((const as1_u32*)(uintptr_t)g,
                                     (as3_u32*)(uintptr_t)lds, 16, 0, 0);
}

// ---------------- wbf pack: 64x64 LDS transpose, both sides coalesced ----------------
// old path read ew1 at 1KB stride (16x overfetch). Range boundaries 2048/2304/2432
// are 64-aligned so each 64-wide n-tile stays in one source matrix.

__global__ void k_packwt(const float* __restrict__ ew1, const float* __restrict__ sw1,
                         const float* __restrict__ rw1, const float* __restrict__ vw1,
                         u16* __restrict__ wbf) {
    __shared__ float t[64][65];
    const int nt = blockIdx.x >> 4, kt = blockIdx.x & 15;
    const int n0 = nt * 64, k0 = kt * 64;
    const int tx = threadIdx.x & 63, ty = threadIdx.x >> 6;
#pragma unroll 4
    for (int it = 0; it < 16; ++it) {
        const int k = k0 + ty + it * 4;
        const int n = n0 + tx;
        float v;
        if (n0 < 2048)      v = ew1[(size_t)((n0 >> 8) * H_DIM + k) * ED_DIM + (n & 255)];
        else if (n0 < 2304) v = sw1[(size_t)k * ED_DIM + (n - 2048)];
        else if (n0 < 2432) v = rw1[(size_t)k * RH_DIM + (n - 2304)];
        else                v = vw1[(size_t)k * RH_DIM + (n - 2432)];
        t[ty + it * 4][tx] = v;
    }
    __syncthreads();
#pragma unroll 4
    for (int it = 0; it < 16; ++it) {
        const int nl = ty + it * 4;
        wbf[(size_t)(n0 + nl) * H_DIM + k0 + tx] = f2bf(t[tx][nl]);
    }
}

// ---------------- merged setup kernel (w2t | w1b | w2b | bias | cand | convert) ----------------

#define SB_W2T (A_DIM * K2)
#define SB_W1B (SB_W2T + 4096)
#define SB_W2B (SB_W1B + 4352)
#define SB_BIA (SB_W2B + NBIG)
#define SB_CND (SB_BIA + T_TOT * E_NUM * A_DIM)

__global__ void k_setup(const float* __restrict__ eb1, const float* __restrict__ sb1,
                        const float* __restrict__ rb1, const float* __restrict__ vb1,
                        const float* __restrict__ ew2, const float* __restrict__ sw2,
                        const float* __restrict__ mw1, const float* __restrict__ mw2,
                        const float* __restrict__ base, const float* __restrict__ state,
                        float* __restrict__ biascat,
                        u16* __restrict__ w2t, u16* __restrict__ w1b, u16* __restrict__ w2b,
                        float* __restrict__ cand_out, u16* __restrict__ xb, int nconv4) {
    int i = blockIdx.x * blockDim.x + threadIdx.x;
    if (i < SB_W2T) {
        int a = i / K2, d = i - a * K2;
        float v = (d < 2048) ? ew2[(size_t)d * A_DIM + a] : sw2[(size_t)(d - 2048) * A_DIM + a];
        w2t[i] = f2bf(v);
    } else if (i < SB_W1B) {
        int t = i - SB_W2T;                      // mw1 [32][128] straight
        w1b[t] = f2bf(mw1[t]);
    } else if (i < SB_W2B) {
        int t = i - SB_W1B;                      // w2b[c][j] padded [32][136], = mw2[j][c]
        int c = t / 136, j = t - c * 136;
        w2b[t] = (j < RH_DIM) ? f2bf(mw2[(size_t)j * A_DIM + c]) : (u16)0;
    } else if (i < SB_BIA) {
        int n = i - SB_W2B;
        float b;
        if (n < 2048)      b = eb1[(n >> 8) * ED_DIM + (n & 255)];
        else if (n < 2304) b = sb1[n - 2048];
        else if (n < 2432) b = rb1[n - 2304];
        else               b = vb1[n - 2432];
        biascat[n] = b;
    } else if (i < SB_CND) {
        int t = i - SB_BIA;
        int a = t & 31, e = (t >> 5) & 7, tt = t >> 8;
        cand_out[t] = base[(size_t)tt * A_DIM + a] * (0.8f + 0.4f * (float)e / 7.0f);
    } else if (i < SB_CND + nconv4) {
        int t = i - SB_CND;
        float4 v = ((const float4*)state)[t];
        ushort4 o;
        o.x = f2bf(v.x); o.y = f2bf(v.y); o.z = f2bf(v.z); o.w = f2bf(v.w);
        ((ushort4*)xb)[t] = o;
    }
}

// fallback converter for chunked mode
__global__ void k_convert_x(const float* __restrict__ x, u16* __restrict__ xb, int n4) {
    int i = blockIdx.x * blockDim.x + threadIdx.x;
    if (i >= n4) return;
    float4 v = ((const float4*)x)[i];
    ushort4 o;
    o.x = f2bf(v.x); o.y = f2bf(v.y); o.z = f2bf(v.z); o.w = f2bf(v.w);
    ((ushort4*)xb)[i] = o;
}

// ---------------- GEMM1: X[Tx1024] @ Wbig -> H1 + fused router/value ----------------
// Main loop: m201-style 8-phase ring, verbatim (verified rounds 7-10).

#define SLOT 8192   // u16 per 16KB slot (128 rows x 64)

__launch_bounds__(512, 2)
__global__ void k_gemm1(const u16* __restrict__ xb, const u16* __restrict__ wbf,
                        const float* __restrict__ biascat, u16* __restrict__ h1,
                        const float* __restrict__ rw2, const float* __restrict__ rb2,
                        const float* __restrict__ vw2, const float* __restrict__ vb2,
                        float* __restrict__ probs_out, float* __restrict__ rtg_out) {
    __shared__ u16 smem[8 * SLOT];   // 128 KB
    __shared__ float rw2s[RH_DIM * E_NUM];
    __shared__ float vws[RH_DIM];
    __shared__ float rb2s[E_NUM];
    const int tid = threadIdx.x;
    const int wid = tid >> 6;
    const int lane = tid & 63;
    const int lin = blockIdx.x;
    const int swz = (lin & 7) * ((int)gridDim.x >> 3) + (lin >> 3);
    const int bx = swz % 10;            // n-tile (NBIG/256 = 10)
    const int by = swz / 10;            // m-tile
    const int m0 = by * 256, n0 = bx * 256;
    const int wr = wid >> 2;
    const int wc = wid & 3;
    const int srow = tid >> 3;
    const int cs = 8 * ((tid & 7) ^ (srow & 7));
    const int l15 = lane & 15;
    const int rsw = (lane & 7) * 8;
    const int lh8 = (lane >> 4) * 8;
    const int c0 = lh8 ^ rsw;
    const int c1 = (32 + lh8) ^ rsw;
    const int aRd = (wr * 16 + l15) * 64;
    const int bRd = ((wc & 1) * 64 + l15) * 64;
    const int bSlotHi = wc >> 1;

    f32x4 acc[8][4];
#pragma unroll
    for (int j = 0; j < 8; ++j)
#pragma unroll
        for (int n = 0; n < 4; ++n) acc[j][n] = (f32x4){0.f, 0.f, 0.f, 0.f};

    auto stageA = [&](int h, int kt, int s) {
        const u16* src = xb + (size_t)(m0 + h * 128 + srow) * H_DIM + kt * 64 + cs;
        u16* dst = smem + s * SLOT + wid * 512;
        gload_lds16(src, dst);
        gload_lds16(src + (size_t)64 * H_DIM, dst + 4096);
    };
    auto stageB = [&](int h, int kt, int s) {
        const u16* src = wbf + (size_t)(n0 + h * 128 + srow) * H_DIM + kt * 64 + cs;
        u16* dst = smem + s * SLOT + wid * 512;
        gload_lds16(src, dst);
        gload_lds16(src + (size_t)64 * H_DIM, dst + 4096);
    };

    bf16x8 bfr[4][2];

#define G1_READA(q, P, A0, A1)                                                    \
    {                                                                             \
        const u16* ab0 = smem + ((P) * 4 + ((q) >> 1)) * SLOT + aRd + (((2*(q)) & 3) * 2048);     \
        const u16* ab1 = smem + ((P) * 4 + ((q) >> 1)) * SLOT + aRd + (((2*(q)+1) & 3) * 2048);   \
        A0[0] = *(const bf16x8*)&ab0[c0]; A0[1] = *(const bf16x8*)&ab0[c1];       \
        A1[0] = *(const bf16x8*)&ab1[c0]; A1[1] = *(const bf16x8*)&ab1[c1];       \
    }

#define G1_MFMA(q, A0, A1)                                                        \
    _Pragma("unroll")                                                             \
    for (int ni = 0; ni < 4; ++ni) {                                              \
        acc[2*(q)][ni]   = __builtin_amdgcn_mfma_f32_16x16x32_bf16(A0[0], bfr[ni][0], acc[2*(q)][ni], 0, 0, 0);   \
        acc[2*(q)][ni]   = __builtin_amdgcn_mfma_f32_16x16x32_bf16(A0[1], bfr[ni][1], acc[2*(q)][ni], 0, 0, 0);   \
        acc[2*(q)+1][ni] = __builtin_amdgcn_mfma_f32_16x16x32_bf16(A1[0], bfr[ni][0], acc[2*(q)+1][ni], 0, 0, 0); \
        acc[2*(q)+1][ni] = __builtin_amdgcn_mfma_f32_16x16x32_bf16(A1[1], bfr[ni][1], acc[2*(q)+1][ni], 0, 0, 0); \
    }

    stageB(0, 0, 2); stageB(1, 0, 3);
    stageA(0, 0, 0); stageA(1, 0, 1);
    stageB(0, 1, 6); stageB(1, 1, 7);
    asm volatile("s_waitcnt vmcnt(6)" ::: "memory");
    __builtin_amdgcn_s_barrier();

#pragma unroll 2
    for (int kt = 0; kt < 16; ++kt) {
        const int p = kt & 1;
        const int ktA = (kt + 1) & 15;
        const int ktB = (kt + 2) & 15;
        const int pA = ktA & 1;
        bf16x8 a0[2], a1[2];
        // ---- P0
        G1_READA(0, p, a0, a1)
#pragma unroll
        for (int ni = 0; ni < 4; ++ni) {
            const u16* bb = smem + (p * 4 + 2 + bSlotHi) * SLOT + bRd + ni * 1024;
            bfr[ni][0] = *(const bf16x8*)&bb[c0];
            bfr[ni][1] = *(const bf16x8*)&bb[c1];
        }
        stageA(0, ktA, pA * 4);
        __builtin_amdgcn_s_barrier();
        asm volatile("s_waitcnt lgkmcnt(0)" ::: "memory");
        __builtin_amdgcn_sched_barrier(0);
        __builtin_amdgcn_s_setprio(1);
        G1_MFMA(0, a0, a1)
        __builtin_amdgcn_s_setprio(0);
        // ---- P1
        G1_READA(1, p, a0, a1)
        stageA(1, ktA, pA * 4 + 1);
        asm volatile("s_waitcnt vmcnt(8)" ::: "memory");
        __builtin_amdgcn_s_barrier();
        asm volatile("s_waitcnt lgkmcnt(0)" ::: "memory");
        __builtin_amdgcn_sched_barrier(0);
        __builtin_amdgcn_s_setprio(1);
        G1_MFMA(1, a0, a1)
        __builtin_amdgcn_s_setprio(0);
        // ---- P2
        G1_READA(2, p, a0, a1)
        stageB(0, ktB, p * 4 + 2);
        __builtin_amdgcn_s_barrier();
        asm volatile("s_waitcnt lgkmcnt(0)" ::: "memory");
        __builtin_amdgcn_sched_barrier(0);
        __builtin_amdgcn_s_setprio(1);
        G1_MFMA(2, a0, a1)
        __builtin_amdgcn_s_setprio(0);
        // ---- P3
        G1_READA(3, p, a0, a1)
        stageB(1, ktB, p * 4 + 3);
        asm volatile("s_waitcnt vmcnt(6)" ::: "memory");
        __builtin_amdgcn_s_barrier();
        asm volatile("s_waitcnt lgkmcnt(0)" ::: "memory");
        __builtin_amdgcn_sched_barrier(0);
        __builtin_amdgcn_s_setprio(1);
        G1_MFMA(3, a0, a1)
        __builtin_amdgcn_s_setprio(0);
    }
#undef G1_READA
#undef G1_MFMA

    const int crow = (lane >> 4) * 4;
    if (bx != 9) {
#pragma unroll
        for (int j = 0; j < 8; ++j) {
#pragma unroll
            for (int ni = 0; ni < 4; ++ni) {
                const int col = n0 + wc * 64 + ni * 16 + l15;
                const float bias = biascat[col];
#pragma unroll
                for (int r = 0; r < 4; ++r) {
                    const int row = m0 + wr * 16 + j * 32 + crow + r;
                    h1[(size_t)row * NBIG + col] = f2bf(gelu_fast(acc[j][ni][r] + bias));
                }
            }
        }
    } else {
        // fused router + value head
        __syncthreads();   // all waves done reading smem (block-uniform branch)
        for (int i = tid; i < RH_DIM * E_NUM; i += 512) rw2s[i] = rw2[i];
        if (tid < RH_DIM) vws[tid] = vw2[tid];
        if (tid < E_NUM) rb2s[tid] = rb2[tid];
        char* sb = (char*)smem;
#pragma unroll
        for (int j = 0; j < 8; ++j) {
#pragma unroll
            for (int ni = 0; ni < 4; ++ni) {
                const int col = wc * 64 + ni * 16 + l15;
                const float bias = biascat[2304 + col];
#pragma unroll
                for (int r = 0; r < 4; ++r) {
                    const int row = wr * 16 + j * 32 + crow + r;
                    float v = acc[j][ni][r] + bias;
                    v = (col < 128) ? gelu_fast(v) : fmaxf(v, 0.f);
                    *(u16*)(sb + row * 512 + ((col * 2) ^ ((row & 31) << 4))) = f2bf(v);
                }
            }
        }
        __syncthreads();
        if (tid < 256) {
            const int row = tid;
            float lg[E_NUM];
#pragma unroll
            for (int e = 0; e < E_NUM; ++e) lg[e] = rb2s[e];
            const int rx = (row & 31) << 4;
#pragma unroll 4
            for (int s = 0; s < 16; ++s) {
                u16x8 v8 = *(const u16x8*)(sb + row * 512 + ((s << 4) ^ rx));
#pragma unroll
                for (int q = 0; q < 8; ++q) {
                    const float xv = bf2f(v8[q]);
                    const float* wr8 = &rw2s[(s * 8 + q) * E_NUM];
#pragma unroll
                    for (int e = 0; e < E_NUM; ++e) lg[e] = fmaf(xv, wr8[e], lg[e]);
                }
            }
            float mx = lg[0];
#pragma unroll
            for (int e = 1; e < E_NUM; ++e) mx = fmaxf(mx, lg[e]);
            float sm = 0.f;
            float ex[E_NUM];
#pragma unroll
            for (int e = 0; e < E_NUM; ++e) { ex[e] = __expf(lg[e] - mx); sm += ex[e]; }
            const float rs = 1.0f / sm;
#pragma unroll
            for (int e = 0; e < E_NUM; ++e) probs_out[(size_t)(m0 + row) * E_NUM + e] = ex[e] * rs;
        } else {
            const int row = tid - 256;
            const int rx = (row & 31) << 4;
            float pv = 0.f;
#pragma unroll 4
            for (int s = 16; s < 32; ++s) {
                u16x8 v8 = *(const u16x8*)(sb + row * 512 + ((s << 4) ^ rx));
#pragma unroll
                for (int q = 0; q < 8; ++q) pv = fmaf(bf2f(v8[q]), vws[(s - 16) * 8 + q], pv);
            }
            rtg_out[m0 + row] = 1.f / (1.f + __expf(-(pv + vb2[0])));
        }
    }
}

// ---------------- GEMM2: 3-deep ring + counted vmcnt, fused prob-fold + residual MLP + final ----------------
// LDS union 38912 B -> 4 blocks/CU (16 waves) AND 2-tiles-ahead prefetch:
//   K-loop:  ring 3 x 12288 B @0  (buf b: A 64x64 @ b*12288, B 32x64 @ +8192B)
//            plds 2048 B @36864
//   epilogue: Am[64][36] @0 | rhm[64][136] @4608 | w1s[32][128] @22016 | w2s[32][136] @30208
// vmcnt accounting exact: only in-loop VMEM = 3 gload_lds/stage; pre-loop
// __syncthreads drains plds loads. vmcnt(3)@iter kt retires stage(kt), leaves
// stage(kt+1) in flight; barrier then allows stage(kt+2) into buf (kt-1)%3
// whose readers finished compute(kt-1) before crossing this barrier.
// Strides 36/136/136 break the old 32-way w2s bank conflict (now 2-way).

__launch_bounds__(256, 4)
__global__ void k_gemm2(const u16* __restrict__ h1, const u16* __restrict__ w2t,
                        const float* __restrict__ probs,
                        const float* __restrict__ eb2, const float* __restrict__ sb2,
                        const u16* __restrict__ w1b, const u16* __restrict__ w2b,
                        const float* __restrict__ mb1, const float* __restrict__ mb2,
                        const float* __restrict__ mask, float* __restrict__ out_final) {
    __shared__ __align__(16) char uni[38912];
    u16* ring = (u16*)uni;
    float* plds = (float*)(uni + 36864);
    const int tid = threadIdx.x;
    const int wid = tid >> 6;
    const int lane = tid & 63;
    const int m0 = blockIdx.x * 64;
    const int csrc = 8 * ((tid & 7) ^ ((tid >> 3) & 7));
    const int rxor = (lane & 7) * 8;
    const int lhi8 = (lane >> 4) * 8;
    const int crow = (lane >> 4) * 4;
    const int ccol = lane & 15;
    const int l15 = lane & 15;

    for (int i = tid; i < 64 * E_NUM; i += 256) plds[i] = probs[(size_t)m0 * E_NUM + i];
    __syncthreads();   // drain all VMEM: in-loop vmcnt accounting is exact from here

    f32x4 accE[2], accT[2], accS[2];
#pragma unroll
    for (int n = 0; n < 2; ++n) {
        accE[n] = (f32x4){0.f, 0.f, 0.f, 0.f};
        accT[n] = (f32x4){0.f, 0.f, 0.f, 0.f};
        accS[n] = (f32x4){0.f, 0.f, 0.f, 0.f};
    }

    auto stage = [&](int buf, int kt) {   // 3 gload_lds per thread
        const int k0 = kt * 64;
        u16* A = ring + buf * 6144;
#pragma unroll
        for (int j = 0; j < 2; ++j)
            gload_lds16(h1 + (size_t)(m0 + j * 32 + (tid >> 3)) * NBIG + k0 + csrc,
                        A + j * 2048 + wid * 512);
        gload_lds16(w2t + (size_t)(tid >> 3) * K2 + k0 + csrc, A + 4096 + wid * 512);
    };

    stage(0, 0);
    stage(1, 1);
    for (int kt = 0; kt < 36; ++kt) {
        if (kt < 35) asm volatile("s_waitcnt vmcnt(3)" ::: "memory");
        else         asm volatile("s_waitcnt vmcnt(0)" ::: "memory");
        __builtin_amdgcn_s_barrier();
        if (kt < 34) stage((kt + 2) % 3, kt + 2);
        const u16* A = ring + (kt % 3) * 6144;
        const bool isExp = (kt < 32);
#pragma unroll
        for (int kk = 0; kk < 64; kk += 32) {
            bf16x8 av = *(const bf16x8*)&A[(wid * 16 + l15) * 64 + ((kk + lhi8) ^ rxor)];
            bf16x8 bv0 = *(const bf16x8*)&A[4096 + l15 * 64 + ((kk + lhi8) ^ rxor)];
            bf16x8 bv1 = *(const bf16x8*)&A[4096 + (16 + l15) * 64 + ((kk + lhi8) ^ rxor)];
            if (isExp) {
                accE[0] = __builtin_amdgcn_mfma_f32_16x16x32_bf16(av, bv0, accE[0], 0, 0, 0);
                accE[1] = __builtin_amdgcn_mfma_f32_16x16x32_bf16(av, bv1, accE[1], 0, 0, 0);
            } else {
                accS[0] = __builtin_amdgcn_mfma_f32_16x16x32_bf16(av, bv0, accS[0], 0, 0, 0);
                accS[1] = __builtin_amdgcn_mfma_f32_16x16x32_bf16(av, bv1, accS[1], 0, 0, 0);
            }
        }
        if (isExp && (kt & 3) == 3) {
            const int e = kt >> 2;
#pragma unroll
            for (int r = 0; r < 4; ++r) {
                const float p = plds[(wid * 16 + crow + r) * E_NUM + e];
#pragma unroll
                for (int n = 0; n < 2; ++n) {
                    accT[n][r] += p * accE[n][r];
                    accE[n][r] = 0.f;
                }
            }
        }
    }

    // ---- E1: wgt in regs; moe -> Am (Am@[0,4608) disjoint from buf2 readers)
    u16* Am  = (u16*)uni;
    u16* rhm = (u16*)(uni + 4608);
    u16* w1s = (u16*)(uni + 22016);
    u16* w2s = (u16*)(uni + 30208);
    float wgt[2][4];
#pragma unroll
    for (int n = 0; n < 2; ++n) {
        const int aIdx = n * 16 + ccol;
#pragma unroll
        for (int r = 0; r < 4; ++r) {
            const int row = wid * 16 + crow + r;
            float wb = 0.f;
#pragma unroll
            for (int e = 0; e < E_NUM; ++e) wb += plds[row * E_NUM + e] * eb2[e * A_DIM + aIdx];
            const float w = accT[n][r] + wb;
            wgt[n][r] = w;
            Am[row * 36 + aIdx] = f2bf(w + accS[n][r] + sb2[aIdx]);   // moe
        }
    }
    __syncthreads();
    // ---- E2: load MLP weights into dead ring space, then pass 1
#pragma unroll
    for (int c = 0; c < 2; ++c)
        gload_lds16(w1b + c * 2048 + (size_t)tid * 8, (char*)w1s + c * 4096 + wid * 1024);
    for (int i = tid; i < 544; i += 256)
        *(u16x8*)&w2s[i * 8] = *(const u16x8*)&w2b[i * 8];
    __syncthreads();   // drains gload (vmcnt) + ds writes
    {
        const int row = tid >> 2, seg = tid & 3;
        const int jb = seg * 32;
#pragma unroll
        for (int h = 0; h < 2; ++h) {
            const int j0 = jb + h * 16;
            float s[16];
#pragma unroll
            for (int q = 0; q < 16; ++q) s[q] = mb1[j0 + q];
#pragma unroll
            for (int a = 0; a < 32; ++a) {
                const float m = bf2f(Am[row * 36 + a]);
                u16x8 wv0 = *(const u16x8*)&w1s[a * 128 + j0];
                u16x8 wv1 = *(const u16x8*)&w1s[a * 128 + j0 + 8];
#pragma unroll
                for (int q = 0; q < 8; ++q) {
                    s[q] = fmaf(m, bf2f(wv0[q]), s[q]);
                    s[8 + q] = fmaf(m, bf2f(wv1[q]), s[8 + q]);
                }
            }
#pragma unroll
            for (int q = 0; q < 16; ++q) rhm[row * 136 + j0 + q] = f2bf(gelu_fast(s[q]));
        }
    }
    __syncthreads();
    // ---- E3: final = wgt + rh @ mw2 + mb2, masked
#pragma unroll
    for (int n = 0; n < 2; ++n) {
        const int aIdx = n * 16 + ccol;
        const float b2 = mb2[aIdx];
#pragma unroll
        for (int r = 0; r < 4; ++r) {
            const int row = wid * 16 + crow + r;
            float s = b2;
#pragma unroll
            for (int jc = 0; jc < 16; ++jc) {
                u16x8 rv = *(const u16x8*)&rhm[row * 136 + jc * 8];
                u16x8 wv = *(const u16x8*)&w2s[aIdx * 136 + jc * 8];
#pragma unroll
                for (int q = 0; q < 8; ++q) s = fmaf(bf2f(rv[q]), bf2f(wv[q]), s);
            }
            const int t = m0 + row;
            out_final[(size_t)t * A_DIM + aIdx] = (wgt[n][r] + s) * mask[t];
        }
    }
}

// ---------------- launch ----------------

extern "C" void kernel_launch(void* const* d_in, const int* in_sizes, int n_in,
                              void* d_out, int out_size, void* d_ws, size_t ws_size,
                              hipStream_t stream) {
    const float* state = (const float*)d_in[0];
    const float* base  = (const float*)d_in[1];
    const float* mask  = (const float*)d_in[2];
    const float* sw1 = (const float*)d_in[3];
    const float* sb1 = (const float*)d_in[4];
    const float* sw2 = (const float*)d_in[5];
    const float* sb2 = (const float*)d_in[6];
    const float* ew1 = (const float*)d_in[7];
    const float* eb1 = (const float*)d_in[8];
    const float* ew2 = (const float*)d_in[9];
    const float* eb2 = (const float*)d_in[10];
    const float* rw1 = (const float*)d_in[11];
    const float* rb1 = (const float*)d_in[12];
    const float* rw2 = (const float*)d_in[13];
    const float* rb2 = (const float*)d_in[14];
    const float* mw1 = (const float*)d_in[15];
    const float* mb1 = (const float*)d_in[16];
    const float* mw2 = (const float*)d_in[17];
    const float* mb2 = (const float*)d_in[18];
    const float* vw1 = (const float*)d_in[19];
    const float* vb1 = (const float*)d_in[20];
    const float* vw2 = (const float*)d_in[21];
    const float* vb2 = (const float*)d_in[22];

    float* out_final = (float*)d_out;                 // [32768][32]
    float* out_cand  = out_final + 1048576;           // [32768][8][32]
    float* out_probs = out_final + 9437184;           // [32768][8]
    float* out_rtg   = out_final + 9699328;           // [32768]

    auto al = [](size_t b) { return (b + 255) & ~(size_t)255; };
    auto need = [&](size_t T) {
        return al((size_t)NBIG * H_DIM * 2) + al((size_t)A_DIM * K2 * 2) + al((size_t)NBIG * 4)
             + al((size_t)4096 * 2) + al((size_t)4352 * 2)
             + al(T * H_DIM * 2) + al(T * NBIG * 2);
    };
    size_t Tc = 8192;
    if (need(32768) <= ws_size)      Tc = 32768;
    else if (need(16384) <= ws_size) Tc = 16384;
    const int nchunk = (int)(T_TOT / Tc);

    char* ws = (char*)d_ws;
    size_t off = 0;
    auto take = [&](size_t b) { char* p = ws + off; off += (b + 255) & ~(size_t)255; return p; };
    u16*   wbf   = (u16*)take((size_t)NBIG * H_DIM * 2);
    u16*   w2t   = (u16*)take((size_t)A_DIM * K2 * 2);
    float* bias  = (float*)take((size_t)NBIG * 4);
    u16*   w1b   = (u16*)take((size_t)4096 * 2);
    u16*   w2b   = (u16*)take((size_t)4352 * 2);
    u16*   xb    = (u16*)take(Tc * H_DIM * 2);
    u16*   h1    = (u16*)take(Tc * NBIG * 2);
    (void)in_sizes; (void)n_in; (void)out_size;

    const int nconv4 = (Tc == 32768) ? (T_TOT * H_DIM / 4) : 0;
    const int ntot = SB_CND + nconv4;
    k_packwt<<<640, 256, 0, stream>>>(ew1, sw1, rw1, vw1, wbf);
    k_setup<<<(ntot + 255) / 256, 256, 0, stream>>>(
        eb1, sb1, rb1, vb1, ew2, sw2, mw1, mw2,
        base, state, bias, w2t, w1b, w2b, out_cand, xb, nconv4);

    for (int c = 0; c < nchunk; ++c) {
        const size_t tb = (size_t)c * Tc;
        if (nconv4 == 0)
            k_convert_x<<<(int)(Tc * H_DIM / 4 / 256), 256, 0, stream>>>(state + tb * H_DIM, xb, (int)(Tc * H_DIM / 4));
        k_gemm1<<<10 * (int)(Tc / 256), 512, 0, stream>>>(xb, wbf, bias, h1,
                                                          rw2, rb2, vw2, vb2,
                                                          out_probs + tb * E_NUM, out_rtg + tb);
        k_gemm2<<<(int)(Tc / 64), 256, 0, stream>>>(h1, w2t, out_probs + tb * E_NUM, eb2, sb2,
                                                    w1b, w2b, mb1, mb2, mask + tb, out_final + tb * A_DIM);
    }
}

// Round 12
// 290.933 us; speedup vs baseline: 1.5953x; 1.5953x over previous
//
#include <hip/hip_runtime.h>
#include <stdint.h>

// Problem dims
#define T_TOT 32768   // B*S
#define H_DIM 1024
#define A_DIM 32
#define E_NUM 8
#define ED_DIM 256
#define RH_DIM 128
#define NBIG 2560     // 8*256 experts + 256 shared + 128 router + 128 value
#define K2 2304       // 8*256 + 256 (expert+shared h1 -> action)

typedef float f32x4 __attribute__((ext_vector_type(4)));
typedef short bf16x8 __attribute__((ext_vector_type(8)));
typedef unsigned short u16;
typedef u16 u16x8 __attribute__((ext_vector_type(8)));

typedef uint32_t __attribute__((address_space(1))) as1_u32;
typedef uint32_t __attribute__((address_space(3))) as3_u32;

__device__ __forceinline__ u16 f2bf(float f) {
    union { float f; uint32_t u; } v; v.f = f;
    return (u16)((v.u + 0x7FFFu + ((v.u >> 16) & 1u)) >> 16);  // RNE
}
__device__ __forceinline__ float bf2f(u16 h) {
    union { uint32_t u; float f; } v; v.u = ((uint32_t)h) << 16;
    return v.f;
}
// tanh-form GELU: x * sigmoid(1.5957691*x*(1+0.044715 x^2)).
__device__ __forceinline__ float gelu_fast(float x) {
    const float x2 = x * x;
    const float s = x * fmaf(0.07135481627f, x2, 1.5957691216f);  // 2z
    const float e = __expf(-s);
    return x * __builtin_amdgcn_rcpf(1.0f + e);
}
__device__ __forceinline__ void gload_lds16(const void* g, void* lds) {
    __builtin_amdgcn_global_load_lds((const as1_u32*)(uintptr_t)g,
                                     (as3_u32*)(uintptr_t)lds, 16, 0, 0);
}

// ---------------- wbf pack: 64x64 LDS transpose, both sides coalesced ----------------

__global__ void k_packwt(const float* __restrict__ ew1, const float* __restrict__ sw1,
                         const float* __restrict__ rw1, const float* __restrict__ vw1,
                         u16* __restrict__ wbf) {
    __shared__ float t[64][65];
    const int nt = blockIdx.x >> 4, kt = blockIdx.x & 15;
    const int n0 = nt * 64, k0 = kt * 64;
    const int tx = threadIdx.x & 63, ty = threadIdx.x >> 6;
#pragma unroll 4
    for (int it = 0; it < 16; ++it) {
        const int k = k0 + ty + it * 4;
        const int n = n0 + tx;
        float v;
        if (n0 < 2048)      v = ew1[(size_t)((n0 >> 8) * H_DIM + k) * ED_DIM + (n & 255)];
        else if (n0 < 2304) v = sw1[(size_t)k * ED_DIM + (n - 2048)];
        else if (n0 < 2432) v = rw1[(size_t)k * RH_DIM + (n - 2304)];
        else                v = vw1[(size_t)k * RH_DIM + (n - 2432)];
        t[ty + it * 4][tx] = v;
    }
    __syncthreads();
#pragma unroll 4
    for (int it = 0; it < 16; ++it) {
        const int nl = ty + it * 4;
        wbf[(size_t)(n0 + nl) * H_DIM + k0 + tx] = f2bf(t[tx][nl]);
    }
}

// ---------------- merged setup kernel (w2t | w1b | w2b | bias | cand | convert) ----------------

#define SB_W2T (A_DIM * K2)
#define SB_W1B (SB_W2T + 4096)
#define SB_W2B (SB_W1B + 4352)
#define SB_BIA (SB_W2B + NBIG)
#define SB_CND (SB_BIA + T_TOT * E_NUM * A_DIM)

__global__ void k_setup(const float* __restrict__ eb1, const float* __restrict__ sb1,
                        const float* __restrict__ rb1, const float* __restrict__ vb1,
                        const float* __restrict__ ew2, const float* __restrict__ sw2,
                        const float* __restrict__ mw1, const float* __restrict__ mw2,
                        const float* __restrict__ base, const float* __restrict__ state,
                        float* __restrict__ biascat,
                        u16* __restrict__ w2t, u16* __restrict__ w1b, u16* __restrict__ w2b,
                        float* __restrict__ cand_out, u16* __restrict__ xb, int nconv4) {
    int i = blockIdx.x * blockDim.x + threadIdx.x;
    if (i < SB_W2T) {
        int a = i / K2, d = i - a * K2;
        float v = (d < 2048) ? ew2[(size_t)d * A_DIM + a] : sw2[(size_t)(d - 2048) * A_DIM + a];
        w2t[i] = f2bf(v);
    } else if (i < SB_W1B) {
        int t = i - SB_W2T;                      // mw1 [32][128] straight
        w1b[t] = f2bf(mw1[t]);
    } else if (i < SB_W2B) {
        int t = i - SB_W1B;                      // w2b[c][j] padded [32][136], = mw2[j][c]
        int c = t / 136, j = t - c * 136;
        w2b[t] = (j < RH_DIM) ? f2bf(mw2[(size_t)j * A_DIM + c]) : (u16)0;
    } else if (i < SB_BIA) {
        int n = i - SB_W2B;
        float b;
        if (n < 2048)      b = eb1[(n >> 8) * ED_DIM + (n & 255)];
        else if (n < 2304) b = sb1[n - 2048];
        else if (n < 2432) b = rb1[n - 2304];
        else               b = vb1[n - 2432];
        biascat[n] = b;
    } else if (i < SB_CND) {
        int t = i - SB_BIA;
        int a = t & 31, e = (t >> 5) & 7, tt = t >> 8;
        cand_out[t] = base[(size_t)tt * A_DIM + a] * (0.8f + 0.4f * (float)e / 7.0f);
    } else if (i < SB_CND + nconv4) {
        int t = i - SB_CND;
        float4 v = ((const float4*)state)[t];
        ushort4 o;
        o.x = f2bf(v.x); o.y = f2bf(v.y); o.z = f2bf(v.z); o.w = f2bf(v.w);
        ((ushort4*)xb)[t] = o;
    }
}

// fallback converter for chunked mode
__global__ void k_convert_x(const float* __restrict__ x, u16* __restrict__ xb, int n4) {
    int i = blockIdx.x * blockDim.x + threadIdx.x;
    if (i >= n4) return;
    float4 v = ((const float4*)x)[i];
    ushort4 o;
    o.x = f2bf(v.x); o.y = f2bf(v.y); o.z = f2bf(v.z); o.w = f2bf(v.w);
    ((ushort4*)xb)[i] = o;
}

// ---------------- GEMM1: X[Tx1024] @ Wbig -> H1 + fused router/value ----------------
// Main loop: m201-style 8-phase ring, verbatim (verified rounds 7-11).

#define SLOT 8192   // u16 per 16KB slot (128 rows x 64)

__launch_bounds__(512, 2)
__global__ void k_gemm1(const u16* __restrict__ xb, const u16* __restrict__ wbf,
                        const float* __restrict__ biascat, u16* __restrict__ h1,
                        const float* __restrict__ rw2, const float* __restrict__ rb2,
                        const float* __restrict__ vw2, const float* __restrict__ vb2,
                        float* __restrict__ probs_out, float* __restrict__ rtg_out) {
    __shared__ u16 smem[8 * SLOT];   // 128 KB
    __shared__ float rw2s[RH_DIM * E_NUM];
    __shared__ float vws[RH_DIM];
    __shared__ float rb2s[E_NUM];
    const int tid = threadIdx.x;
    const int wid = tid >> 6;
    const int lane = tid & 63;
    const int lin = blockIdx.x;
    const int swz = (lin & 7) * ((int)gridDim.x >> 3) + (lin >> 3);
    const int bx = swz % 10;            // n-tile (NBIG/256 = 10)
    const int by = swz / 10;            // m-tile
    const int m0 = by * 256, n0 = bx * 256;
    const int wr = wid >> 2;
    const int wc = wid & 3;
    const int srow = tid >> 3;
    const int cs = 8 * ((tid & 7) ^ (srow & 7));
    const int l15 = lane & 15;
    const int rsw = (lane & 7) * 8;
    const int lh8 = (lane >> 4) * 8;
    const int c0 = lh8 ^ rsw;
    const int c1 = (32 + lh8) ^ rsw;
    const int aRd = (wr * 16 + l15) * 64;
    const int bRd = ((wc & 1) * 64 + l15) * 64;
    const int bSlotHi = wc >> 1;

    f32x4 acc[8][4];
#pragma unroll
    for (int j = 0; j < 8; ++j)
#pragma unroll
        for (int n = 0; n < 4; ++n) acc[j][n] = (f32x4){0.f, 0.f, 0.f, 0.f};

    auto stageA = [&](int h, int kt, int s) {
        const u16* src = xb + (size_t)(m0 + h * 128 + srow) * H_DIM + kt * 64 + cs;
        u16* dst = smem + s * SLOT + wid * 512;
        gload_lds16(src, dst);
        gload_lds16(src + (size_t)64 * H_DIM, dst + 4096);
    };
    auto stageB = [&](int h, int kt, int s) {
        const u16* src = wbf + (size_t)(n0 + h * 128 + srow) * H_DIM + kt * 64 + cs;
        u16* dst = smem + s * SLOT + wid * 512;
        gload_lds16(src, dst);
        gload_lds16(src + (size_t)64 * H_DIM, dst + 4096);
    };

    bf16x8 bfr[4][2];

#define G1_READA(q, P, A0, A1)                                                    \
    {                                                                             \
        const u16* ab0 = smem + ((P) * 4 + ((q) >> 1)) * SLOT + aRd + (((2*(q)) & 3) * 2048);     \
        const u16* ab1 = smem + ((P) * 4 + ((q) >> 1)) * SLOT + aRd + (((2*(q)+1) & 3) * 2048);   \
        A0[0] = *(const bf16x8*)&ab0[c0]; A0[1] = *(const bf16x8*)&ab0[c1];       \
        A1[0] = *(const bf16x8*)&ab1[c0]; A1[1] = *(const bf16x8*)&ab1[c1];       \
    }

#define G1_MFMA(q, A0, A1)                                                        \
    _Pragma("unroll")                                                             \
    for (int ni = 0; ni < 4; ++ni) {                                              \
        acc[2*(q)][ni]   = __builtin_amdgcn_mfma_f32_16x16x32_bf16(A0[0], bfr[ni][0], acc[2*(q)][ni], 0, 0, 0);   \
        acc[2*(q)][ni]   = __builtin_amdgcn_mfma_f32_16x16x32_bf16(A0[1], bfr[ni][1], acc[2*(q)][ni], 0, 0, 0);   \
        acc[2*(q)+1][ni] = __builtin_amdgcn_mfma_f32_16x16x32_bf16(A1[0], bfr[ni][0], acc[2*(q)+1][ni], 0, 0, 0); \
        acc[2*(q)+1][ni] = __builtin_amdgcn_mfma_f32_16x16x32_bf16(A1[1], bfr[ni][1], acc[2*(q)+1][ni], 0, 0, 0); \
    }

    stageB(0, 0, 2); stageB(1, 0, 3);
    stageA(0, 0, 0); stageA(1, 0, 1);
    stageB(0, 1, 6); stageB(1, 1, 7);
    asm volatile("s_waitcnt vmcnt(6)" ::: "memory");
    __builtin_amdgcn_s_barrier();

#pragma unroll 2
    for (int kt = 0; kt < 16; ++kt) {
        const int p = kt & 1;
        const int ktA = (kt + 1) & 15;
        const int ktB = (kt + 2) & 15;
        const int pA = ktA & 1;
        bf16x8 a0[2], a1[2];
        // ---- P0
        G1_READA(0, p, a0, a1)
#pragma unroll
        for (int ni = 0; ni < 4; ++ni) {
            const u16* bb = smem + (p * 4 + 2 + bSlotHi) * SLOT + bRd + ni * 1024;
            bfr[ni][0] = *(const bf16x8*)&bb[c0];
            bfr[ni][1] = *(const bf16x8*)&bb[c1];
        }
        stageA(0, ktA, pA * 4);
        __builtin_amdgcn_s_barrier();
        asm volatile("s_waitcnt lgkmcnt(0)" ::: "memory");
        __builtin_amdgcn_sched_barrier(0);
        __builtin_amdgcn_s_setprio(1);
        G1_MFMA(0, a0, a1)
        __builtin_amdgcn_s_setprio(0);
        // ---- P1
        G1_READA(1, p, a0, a1)
        stageA(1, ktA, pA * 4 + 1);
        asm volatile("s_waitcnt vmcnt(8)" ::: "memory");
        __builtin_amdgcn_s_barrier();
        asm volatile("s_waitcnt lgkmcnt(0)" ::: "memory");
        __builtin_amdgcn_sched_barrier(0);
        __builtin_amdgcn_s_setprio(1);
        G1_MFMA(1, a0, a1)
        __builtin_amdgcn_s_setprio(0);
        // ---- P2
        G1_READA(2, p, a0, a1)
        stageB(0, ktB, p * 4 + 2);
        __builtin_amdgcn_s_barrier();
        asm volatile("s_waitcnt lgkmcnt(0)" ::: "memory");
        __builtin_amdgcn_sched_barrier(0);
        __builtin_amdgcn_s_setprio(1);
        G1_MFMA(2, a0, a1)
        __builtin_amdgcn_s_setprio(0);
        // ---- P3
        G1_READA(3, p, a0, a1)
        stageB(1, ktB, p * 4 + 3);
        asm volatile("s_waitcnt vmcnt(6)" ::: "memory");
        __builtin_amdgcn_s_barrier();
        asm volatile("s_waitcnt lgkmcnt(0)" ::: "memory");
        __builtin_amdgcn_sched_barrier(0);
        __builtin_amdgcn_s_setprio(1);
        G1_MFMA(3, a0, a1)
        __builtin_amdgcn_s_setprio(0);
    }
#undef G1_READA
#undef G1_MFMA

    const int crow = (lane >> 4) * 4;
    if (bx != 9) {
#pragma unroll
        for (int j = 0; j < 8; ++j) {
#pragma unroll
            for (int ni = 0; ni < 4; ++ni) {
                const int col = n0 + wc * 64 + ni * 16 + l15;
                const float bias = biascat[col];
#pragma unroll
                for (int r = 0; r < 4; ++r) {
                    const int row = m0 + wr * 16 + j * 32 + crow + r;
                    h1[(size_t)row * NBIG + col] = f2bf(gelu_fast(acc[j][ni][r] + bias));
                }
            }
        }
    } else {
        // fused router + value head
        __syncthreads();   // all waves done reading smem (block-uniform branch)
        for (int i = tid; i < RH_DIM * E_NUM; i += 512) rw2s[i] = rw2[i];
        if (tid < RH_DIM) vws[tid] = vw2[tid];
        if (tid < E_NUM) rb2s[tid] = rb2[tid];
        char* sb = (char*)smem;
#pragma unroll
        for (int j = 0; j < 8; ++j) {
#pragma unroll
            for (int ni = 0; ni < 4; ++ni) {
                const int col = wc * 64 + ni * 16 + l15;
                const float bias = biascat[2304 + col];
#pragma unroll
                for (int r = 0; r < 4; ++r) {
                    const int row = wr * 16 + j * 32 + crow + r;
                    float v = acc[j][ni][r] + bias;
                    v = (col < 128) ? gelu_fast(v) : fmaxf(v, 0.f);
                    *(u16*)(sb + row * 512 + ((col * 2) ^ ((row & 31) << 4))) = f2bf(v);
                }
            }
        }
        __syncthreads();
        if (tid < 256) {
            const int row = tid;
            float lg[E_NUM];
#pragma unroll
            for (int e = 0; e < E_NUM; ++e) lg[e] = rb2s[e];
            const int rx = (row & 31) << 4;
#pragma unroll 4
            for (int s = 0; s < 16; ++s) {
                u16x8 v8 = *(const u16x8*)(sb + row * 512 + ((s << 4) ^ rx));
#pragma unroll
                for (int q = 0; q < 8; ++q) {
                    const float xv = bf2f(v8[q]);
                    const float* wr8 = &rw2s[(s * 8 + q) * E_NUM];
#pragma unroll
                    for (int e = 0; e < E_NUM; ++e) lg[e] = fmaf(xv, wr8[e], lg[e]);
                }
            }
            float mx = lg[0];
#pragma unroll
            for (int e = 1; e < E_NUM; ++e) mx = fmaxf(mx, lg[e]);
            float sm = 0.f;
            float ex[E_NUM];
#pragma unroll
            for (int e = 0; e < E_NUM; ++e) { ex[e] = __expf(lg[e] - mx); sm += ex[e]; }
            const float rs = 1.0f / sm;
#pragma unroll
            for (int e = 0; e < E_NUM; ++e) probs_out[(size_t)(m0 + row) * E_NUM + e] = ex[e] * rs;
        } else {
            const int row = tid - 256;
            const int rx = (row & 31) << 4;
            float pv = 0.f;
#pragma unroll 4
            for (int s = 16; s < 32; ++s) {
                u16x8 v8 = *(const u16x8*)(sb + row * 512 + ((s << 4) ^ rx));
#pragma unroll
                for (int q = 0; q < 8; ++q) pv = fmaf(bf2f(v8[q]), vws[(s - 16) * 8 + q], pv);
            }
            rtg_out[m0 + row] = 1.f / (1.f + __expf(-(pv + vb2[0])));
        }
    }
}

// ---------------- GEMM2: H1[Tx2304] @ W2T^T + prob fold + fused residual MLP + final ----------------
// REVERTED to the round-10 verified structure (2-phase __syncthreads dbuf,
// launch_bounds(256,3)). Round-11's 3-ring/counted-vmcnt variant scratch-spilled
// (WRITE_SIZE 373 MB, MfmaUtil 0.8%) — see round-11 post-mortem.
// Single diff vs round-10: w2s stride 128 -> 136 (padded w2b) to break the
// 32-way bank conflict on the E3 w2s reads (now 2-way = free).

__launch_bounds__(256, 3)
__global__ void k_gemm2(const u16* __restrict__ h1, const u16* __restrict__ w2t,
                        const float* __restrict__ probs,
                        const float* __restrict__ eb2, const float* __restrict__ sb2,
                        const u16* __restrict__ w1b, const u16* __restrict__ w2b,
                        const float* __restrict__ mb1, const float* __restrict__ mb2,
                        const float* __restrict__ mask, float* __restrict__ out_final) {
    __shared__ u16 uni[12288];          // As[2]@0 (4096 each), Bs[2]@8192 (2048 each); epilogue: Am@0, rh@2560
    __shared__ float plds[64 * E_NUM];
    __shared__ u16 w1s[32 * 128];       // mw1 bf16 [32][128]
    __shared__ u16 w2s[32 * 136];       // mw2^T bf16 [32 cols][136 j padded]
    const int tid = threadIdx.x;
    const int wid = tid >> 6;
    const int lane = tid & 63;
    const int m0 = blockIdx.x * 64;
    const int csrc = 8 * ((tid & 7) ^ ((tid >> 3) & 7));
    const int rxor = (lane & 7) * 8;
    const int lhi8 = (lane >> 4) * 8;
    const int crow = (lane >> 4) * 4;
    const int ccol = lane & 15;

    for (int i = tid; i < 64 * E_NUM; i += 256) plds[i] = probs[(size_t)m0 * E_NUM + i];
    for (int i = tid; i < 4096; i += 256) w1s[i] = w1b[i];
    for (int i = tid; i < 544; i += 256) *(u16x8*)&w2s[i * 8] = *(const u16x8*)&w2b[i * 8];

    f32x4 accE[2], accT[2], accS[2];
#pragma unroll
    for (int n = 0; n < 2; ++n) {
        accE[n] = (f32x4){0.f, 0.f, 0.f, 0.f};
        accT[n] = (f32x4){0.f, 0.f, 0.f, 0.f};
        accS[n] = (f32x4){0.f, 0.f, 0.f, 0.f};
    }

    auto stage = [&](int buf, int kt) {
        const int k0 = kt * 64;
#pragma unroll
        for (int j = 0; j < 2; ++j)
            gload_lds16(h1 + (size_t)(m0 + j * 32 + (tid >> 3)) * NBIG + k0 + csrc,
                        &uni[buf * 4096 + j * 2048 + wid * 512]);
        gload_lds16(w2t + (size_t)(tid >> 3) * K2 + k0 + csrc, &uni[8192 + buf * 2048 + wid * 512]);
    };

    stage(0, 0);
    __syncthreads();
    int cur = 0;
    for (int kt = 0; kt < 36; ++kt) {
        if (kt < 35) stage(cur ^ 1, kt + 1);
        const bool isExp = (kt < 32);
#pragma unroll
        for (int kk = 0; kk < 64; kk += 32) {
            bf16x8 av = *(const bf16x8*)&uni[cur * 4096 + (wid * 16 + (lane & 15)) * 64 + ((kk + lhi8) ^ rxor)];
            bf16x8 bv0 = *(const bf16x8*)&uni[8192 + cur * 2048 + ((lane & 15)) * 64 + ((kk + lhi8) ^ rxor)];
            bf16x8 bv1 = *(const bf16x8*)&uni[8192 + cur * 2048 + (16 + (lane & 15)) * 64 + ((kk + lhi8) ^ rxor)];
            if (isExp) {
                accE[0] = __builtin_amdgcn_mfma_f32_16x16x32_bf16(av, bv0, accE[0], 0, 0, 0);
                accE[1] = __builtin_amdgcn_mfma_f32_16x16x32_bf16(av, bv1, accE[1], 0, 0, 0);
            } else {
                accS[0] = __builtin_amdgcn_mfma_f32_16x16x32_bf16(av, bv0, accS[0], 0, 0, 0);
                accS[1] = __builtin_amdgcn_mfma_f32_16x16x32_bf16(av, bv1, accS[1], 0, 0, 0);
            }
        }
        if (isExp && (kt & 3) == 3) {
            const int e = kt >> 2;
#pragma unroll
            for (int r = 0; r < 4; ++r) {
                const float p = plds[(wid * 16 + crow + r) * E_NUM + e];
#pragma unroll
                for (int n = 0; n < 2; ++n) {
                    accT[n][r] += p * accE[n][r];
                    accE[n][r] = 0.f;
                }
            }
        }
        __syncthreads();
        cur ^= 1;
    }

    // ---- fused epilogue: wgt stays in accT; moe -> LDS bf16; scalar MLP; final out
    u16* Am = uni;            // [64][40]
    u16* rhm = uni + 2560;    // [64][136]
    float wgt[2][4];
#pragma unroll
    for (int n = 0; n < 2; ++n) {
        const int aIdx = n * 16 + ccol;
#pragma unroll
        for (int r = 0; r < 4; ++r) {
            const int row = wid * 16 + crow + r;
            float wb = 0.f;
#pragma unroll
            for (int e = 0; e < E_NUM; ++e) wb += plds[row * E_NUM + e] * eb2[e * A_DIM + aIdx];
            const float w = accT[n][r] + wb;
            wgt[n][r] = w;
            Am[row * 40 + aIdx] = f2bf(w + accS[n][r] + sb2[aIdx]);   // moe
        }
    }
    __syncthreads();
    {   // pass 1: rh[row][j] = gelu(moe_row @ mw1 + mb1), thread = (row, 32-col segment)
        const int row = tid >> 2, seg = tid & 3;
        float mrow[32];
#pragma unroll
        for (int a = 0; a < 32; ++a) mrow[a] = bf2f(Am[row * 40 + a]);
#pragma unroll 4
        for (int jj = 0; jj < 32; ++jj) {
            const int j = seg * 32 + jj;
            float s = mb1[j];
#pragma unroll
            for (int a = 0; a < 32; ++a) s = fmaf(mrow[a], bf2f(w1s[a * 128 + j]), s);
            rhm[row * 136 + j] = f2bf(gelu_fast(s));
        }
    }
    __syncthreads();
    // pass 2: final = wgt + rh @ mw2 + mb2, masked
#pragma unroll
    for (int n = 0; n < 2; ++n) {
        const int aIdx = n * 16 + ccol;
        const float b2 = mb2[aIdx];
#pragma unroll
        for (int r = 0; r < 4; ++r) {
            const int row = wid * 16 + crow + r;
            float s = b2;
#pragma unroll
            for (int jc = 0; jc < 16; ++jc) {
                u16x8 rv = *(const u16x8*)&rhm[row * 136 + jc * 8];
                u16x8 wv = *(const u16x8*)&w2s[aIdx * 136 + jc * 8];
#pragma unroll
                for (int q = 0; q < 8; ++q) s = fmaf(bf2f(rv[q]), bf2f(wv[q]), s);
            }
            const int t = m0 + row;
            out_final[(size_t)t * A_DIM + aIdx] = (wgt[n][r] + s) * mask[t];
        }
    }
}

// ---------------- launch ----------------

extern "C" void kernel_launch(void* const* d_in, const int* in_sizes, int n_in,
                              void* d_out, int out_size, void* d_ws, size_t ws_size,
                              hipStream_t stream) {
    const float* state = (const float*)d_in[0];
    const float* base  = (const float*)d_in[1];
    const float* mask  = (const float*)d_in[2];
    const float* sw1 = (const float*)d_in[3];
    const float* sb1 = (const float*)d_in[4];
    const float* sw2 = (const float*)d_in[5];
    const float* sb2 = (const float*)d_in[6];
    const float* ew1 = (const float*)d_in[7];
    const float* eb1 = (const float*)d_in[8];
    const float* ew2 = (const float*)d_in[9];
    const float* eb2 = (const float*)d_in[10];
    const float* rw1 = (const float*)d_in[11];
    const float* rb1 = (const float*)d_in[12];
    const float* rw2 = (const float*)d_in[13];
    const float* rb2 = (const float*)d_in[14];
    const float* mw1 = (const float*)d_in[15];
    const float* mb1 = (const float*)d_in[16];
    const float* mw2 = (const float*)d_in[17];
    const float* mb2 = (const float*)d_in[18];
    const float* vw1 = (const float*)d_in[19];
    const float* vb1 = (const float*)d_in[20];
    const float* vw2 = (const float*)d_in[21];
    const float* vb2 = (const float*)d_in[22];

    float* out_final = (float*)d_out;                 // [32768][32]
    float* out_cand  = out_final + 1048576;           // [32768][8][32]
    float* out_probs = out_final + 9437184;           // [32768][8]
    float* out_rtg   = out_final + 9699328;           // [32768]

    auto al = [](size_t b) { return (b + 255) & ~(size_t)255; };
    auto need = [&](size_t T) {
        return al((size_t)NBIG * H_DIM * 2) + al((size_t)A_DIM * K2 * 2) + al((size_t)NBIG * 4)
             + al((size_t)4096 * 2) + al((size_t)4352 * 2)
             + al(T * H_DIM * 2) + al(T * NBIG * 2);
    };
    size_t Tc = 8192;
    if (need(32768) <= ws_size)      Tc = 32768;
    else if (need(16384) <= ws_size) Tc = 16384;
    const int nchunk = (int)(T_TOT / Tc);

    char* ws = (char*)d_ws;
    size_t off = 0;
    auto take = [&](size_t b) { char* p = ws + off; off += (b + 255) & ~(size_t)255; return p; };
    u16*   wbf   = (u16*)take((size_t)NBIG * H_DIM * 2);
    u16*   w2t   = (u16*)take((size_t)A_DIM * K2 * 2);
    float* bias  = (float*)take((size_t)NBIG * 4);
    u16*   w1b   = (u16*)take((size_t)4096 * 2);
    u16*   w2b   = (u16*)take((size_t)4352 * 2);
    u16*   xb    = (u16*)take(Tc * H_DIM * 2);
    u16*   h1    = (u16*)take(Tc * NBIG * 2);
    (void)in_sizes; (void)n_in; (void)out_size;

    const int nconv4 = (Tc == 32768) ? (T_TOT * H_DIM / 4) : 0;
    const int ntot = SB_CND + nconv4;
    k_packwt<<<640, 256, 0, stream>>>(ew1, sw1, rw1, vw1, wbf);
    k_setup<<<(ntot + 255) / 256, 256, 0, stream>>>(
        eb1, sb1, rb1, vb1, ew2, sw2, mw1, mw2,
        base, state, bias, w2t, w1b, w2b, out_cand, xb, nconv4);

    for (int c = 0; c < nchunk; ++c) {
        const size_t tb = (size_t)c * Tc;
        if (nconv4 == 0)
            k_convert_x<<<(int)(Tc * H_DIM / 4 / 256), 256, 0, stream>>>(state + tb * H_DIM, xb, (int)(Tc * H_DIM / 4));
        k_gemm1<<<10 * (int)(Tc / 256), 512, 0, stream>>>(xb, wbf, bias, h1,
                                                          rw2, rb2, vw2, vb2,
                                                          out_probs + tb * E_NUM, out_rtg + tb);
        k_gemm2<<<(int)(Tc / 64), 256, 0, stream>>>(h1, w2t, out_probs + tb * E_NUM, eb2, sb2,
                                                    w1b, w2b, mb1, mb2, mask + tb, out_final + tb * A_DIM);
    }
}

// Round 13
// 274.810 us; speedup vs baseline: 1.6888x; 1.0587x over previous
//
#include <hip/hip_runtime.h>
#include <stdint.h>

// Problem dims
#define T_TOT 32768   // B*S
#define H_DIM 1024
#define A_DIM 32
#define E_NUM 8
#define ED_DIM 256
#define RH_DIM 128
#define NBIG 2560     // 8*256 experts + 256 shared + 128 router + 128 value
#define K2 2304       // 8*256 + 256 (expert+shared h1 -> action)

typedef float f32x4 __attribute__((ext_vector_type(4)));
typedef short bf16x8 __attribute__((ext_vector_type(8)));
typedef unsigned short u16;
typedef u16 u16x8 __attribute__((ext_vector_type(8)));

typedef uint32_t __attribute__((address_space(1))) as1_u32;
typedef uint32_t __attribute__((address_space(3))) as3_u32;

__device__ __forceinline__ u16 f2bf(float f) {
    union { float f; uint32_t u; } v; v.f = f;
    return (u16)((v.u + 0x7FFFu + ((v.u >> 16) & 1u)) >> 16);  // RNE
}
__device__ __forceinline__ float bf2f(u16 h) {
    union { uint32_t u; float f; } v; v.u = ((uint32_t)h) << 16;
    return v.f;
}
// tanh-form GELU: x * sigmoid(1.5957691*x*(1+0.044715 x^2)).
__device__ __forceinline__ float gelu_fast(float x) {
    const float x2 = x * x;
    const float s = x * fmaf(0.07135481627f, x2, 1.5957691216f);  // 2z
    const float e = __expf(-s);
    return x * __builtin_amdgcn_rcpf(1.0f + e);
}
__device__ __forceinline__ void gload_lds16(const void* g, void* lds) {
    __builtin_amdgcn_global_load_lds((const as1_u32*)(uintptr_t)g,
                                     (as3_u32*)(uintptr_t)lds, 16, 0, 0);
}

// ---------------- wbf pack: 64x64 LDS transpose, both sides coalesced ----------------

__global__ void k_packwt(const float* __restrict__ ew1, const float* __restrict__ sw1,
                         const float* __restrict__ rw1, const float* __restrict__ vw1,
                         u16* __restrict__ wbf) {
    __shared__ float t[64][65];
    const int nt = blockIdx.x >> 4, kt = blockIdx.x & 15;
    const int n0 = nt * 64, k0 = kt * 64;
    const int tx = threadIdx.x & 63, ty = threadIdx.x >> 6;
#pragma unroll 4
    for (int it = 0; it < 16; ++it) {
        const int k = k0 + ty + it * 4;
        const int n = n0 + tx;
        float v;
        if (n0 < 2048)      v = ew1[(size_t)((n0 >> 8) * H_DIM + k) * ED_DIM + (n & 255)];
        else if (n0 < 2304) v = sw1[(size_t)k * ED_DIM + (n - 2048)];
        else if (n0 < 2432) v = rw1[(size_t)k * RH_DIM + (n - 2304)];
        else                v = vw1[(size_t)k * RH_DIM + (n - 2432)];
        t[ty + it * 4][tx] = v;
    }
    __syncthreads();
#pragma unroll 4
    for (int it = 0; it < 16; ++it) {
        const int nl = ty + it * 4;
        wbf[(size_t)(n0 + nl) * H_DIM + k0 + tx] = f2bf(t[tx][nl]);
    }
}

// ---------------- merged setup kernel (w2t | w1b | w2b | bias | cand | convert) ----------------

#define SB_W2T (A_DIM * K2)
#define SB_W1B (SB_W2T + 4096)
#define SB_W2B (SB_W1B + 4352)
#define SB_BIA (SB_W2B + NBIG)
#define SB_CND (SB_BIA + T_TOT * E_NUM * A_DIM)

__global__ void k_setup(const float* __restrict__ eb1, const float* __restrict__ sb1,
                        const float* __restrict__ rb1, const float* __restrict__ vb1,
                        const float* __restrict__ ew2, const float* __restrict__ sw2,
                        const float* __restrict__ mw1, const float* __restrict__ mw2,
                        const float* __restrict__ base, const float* __restrict__ state,
                        float* __restrict__ biascat,
                        u16* __restrict__ w2t, u16* __restrict__ w1b, u16* __restrict__ w2b,
                        float* __restrict__ cand_out, u16* __restrict__ xb, int nconv4) {
    int i = blockIdx.x * blockDim.x + threadIdx.x;
    if (i < SB_W2T) {
        int a = i / K2, d = i - a * K2;
        float v = (d < 2048) ? ew2[(size_t)d * A_DIM + a] : sw2[(size_t)(d - 2048) * A_DIM + a];
        w2t[i] = f2bf(v);
    } else if (i < SB_W1B) {
        int t = i - SB_W2T;                      // mw1 [32][128] straight
        w1b[t] = f2bf(mw1[t]);
    } else if (i < SB_W2B) {
        int t = i - SB_W1B;                      // w2b[c][j] padded [32][136], = mw2[j][c]
        int c = t / 136, j = t - c * 136;
        w2b[t] = (j < RH_DIM) ? f2bf(mw2[(size_t)j * A_DIM + c]) : (u16)0;
    } else if (i < SB_BIA) {
        int n = i - SB_W2B;
        float b;
        if (n < 2048)      b = eb1[(n >> 8) * ED_DIM + (n & 255)];
        else if (n < 2304) b = sb1[n - 2048];
        else if (n < 2432) b = rb1[n - 2304];
        else               b = vb1[n - 2432];
        biascat[n] = b;
    } else if (i < SB_CND) {
        int t = i - SB_BIA;
        int a = t & 31, e = (t >> 5) & 7, tt = t >> 8;
        cand_out[t] = base[(size_t)tt * A_DIM + a] * (0.8f + 0.4f * (float)e / 7.0f);
    } else if (i < SB_CND + nconv4) {
        int t = i - SB_CND;
        float4 v = ((const float4*)state)[t];
        ushort4 o;
        o.x = f2bf(v.x); o.y = f2bf(v.y); o.z = f2bf(v.z); o.w = f2bf(v.w);
        ((ushort4*)xb)[t] = o;
    }
}

// fallback converter for chunked mode
__global__ void k_convert_x(const float* __restrict__ x, u16* __restrict__ xb, int n4) {
    int i = blockIdx.x * blockDim.x + threadIdx.x;
    if (i >= n4) return;
    float4 v = ((const float4*)x)[i];
    ushort4 o;
    o.x = f2bf(v.x); o.y = f2bf(v.y); o.z = f2bf(v.z); o.w = f2bf(v.w);
    ((ushort4*)xb)[i] = o;
}

// ---------------- GEMM1: X[Tx1024] @ Wbig, fused second GEMM -> Pbuf + fused router/value ----------------
// Main loop: m201-style 8-phase ring, verbatim (verified rounds 7-12).
// Epilogue bx<9 (NEW): Y = gelu(acc+bias) -> smem [256][256] bf16 (slot-XOR
// swizzle, involution slot^(row&15); write 2-way / read 2-way = free), then
// each wave computes P = Y[its 32 rows x 256k] @ w2t-slice[256k x 32] via 32
// MFMAs (wave-private rows -> no cross-wave reduce) and stores f32 partials to
// Pbuf[t][bx][32]. h1 is GONE (was 148.6 MB write + 151 MB read).
// B-frag = 8 consecutive k at col=l15 read straight from w2t (same operand
// convention as main loop's wbf reads). __syncthreads before Y-writes drains
// the in-flight wraparound gload_lds stages (they target smem).
// Epilogue bx==9: fused router+value (verified round 10/12).

#define SLOT 8192   // u16 per 16KB slot (128 rows x 64)

__launch_bounds__(512, 2)
__global__ void k_gemm1(const u16* __restrict__ xb, const u16* __restrict__ wbf,
                        const float* __restrict__ biascat, const u16* __restrict__ w2t,
                        float* __restrict__ Pb,
                        const float* __restrict__ rw2, const float* __restrict__ rb2,
                        const float* __restrict__ vw2, const float* __restrict__ vb2,
                        float* __restrict__ probs_out, float* __restrict__ rtg_out) {
    __shared__ u16 smem[8 * SLOT];   // 128 KB; epilogue: Y [256][256] bf16
    __shared__ float rw2s[RH_DIM * E_NUM];
    __shared__ float vws[RH_DIM];
    __shared__ float rb2s[E_NUM];
    const int tid = threadIdx.x;
    const int wid = tid >> 6;
    const int lane = tid & 63;
    const int lin = blockIdx.x;
    const int swz = (lin & 7) * ((int)gridDim.x >> 3) + (lin >> 3);
    const int bx = swz % 10;            // n-tile (NBIG/256 = 10)
    const int by = swz / 10;            // m-tile
    const int m0 = by * 256, n0 = bx * 256;
    const int wr = wid >> 2;
    const int wc = wid & 3;
    const int srow = tid >> 3;
    const int cs = 8 * ((tid & 7) ^ (srow & 7));
    const int l15 = lane & 15;
    const int rsw = (lane & 7) * 8;
    const int lh8 = (lane >> 4) * 8;
    const int c0 = lh8 ^ rsw;
    const int c1 = (32 + lh8) ^ rsw;
    const int aRd = (wr * 16 + l15) * 64;
    const int bRd = ((wc & 1) * 64 + l15) * 64;
    const int bSlotHi = wc >> 1;

    f32x4 acc[8][4];
#pragma unroll
    for (int j = 0; j < 8; ++j)
#pragma unroll
        for (int n = 0; n < 4; ++n) acc[j][n] = (f32x4){0.f, 0.f, 0.f, 0.f};

    auto stageA = [&](int h, int kt, int s) {
        const u16* src = xb + (size_t)(m0 + h * 128 + srow) * H_DIM + kt * 64 + cs;
        u16* dst = smem + s * SLOT + wid * 512;
        gload_lds16(src, dst);
        gload_lds16(src + (size_t)64 * H_DIM, dst + 4096);
    };
    auto stageB = [&](int h, int kt, int s) {
        const u16* src = wbf + (size_t)(n0 + h * 128 + srow) * H_DIM + kt * 64 + cs;
        u16* dst = smem + s * SLOT + wid * 512;
        gload_lds16(src, dst);
        gload_lds16(src + (size_t)64 * H_DIM, dst + 4096);
    };

    bf16x8 bfr[4][2];

#define G1_READA(q, P, A0, A1)                                                    \
    {                                                                             \
        const u16* ab0 = smem + ((P) * 4 + ((q) >> 1)) * SLOT + aRd + (((2*(q)) & 3) * 2048);     \
        const u16* ab1 = smem + ((P) * 4 + ((q) >> 1)) * SLOT + aRd + (((2*(q)+1) & 3) * 2048);   \
        A0[0] = *(const bf16x8*)&ab0[c0]; A0[1] = *(const bf16x8*)&ab0[c1];       \
        A1[0] = *(const bf16x8*)&ab1[c0]; A1[1] = *(const bf16x8*)&ab1[c1];       \
    }

#define G1_MFMA(q, A0, A1)                                                        \
    _Pragma("unroll")                                                             \
    for (int ni = 0; ni < 4; ++ni) {                                              \
        acc[2*(q)][ni]   = __builtin_amdgcn_mfma_f32_16x16x32_bf16(A0[0], bfr[ni][0], acc[2*(q)][ni], 0, 0, 0);   \
        acc[2*(q)][ni]   = __builtin_amdgcn_mfma_f32_16x16x32_bf16(A0[1], bfr[ni][1], acc[2*(q)][ni], 0, 0, 0);   \
        acc[2*(q)+1][ni] = __builtin_amdgcn_mfma_f32_16x16x32_bf16(A1[0], bfr[ni][0], acc[2*(q)+1][ni], 0, 0, 0); \
        acc[2*(q)+1][ni] = __builtin_amdgcn_mfma_f32_16x16x32_bf16(A1[1], bfr[ni][1], acc[2*(q)+1][ni], 0, 0, 0); \
    }

    stageB(0, 0, 2); stageB(1, 0, 3);
    stageA(0, 0, 0); stageA(1, 0, 1);
    stageB(0, 1, 6); stageB(1, 1, 7);
    asm volatile("s_waitcnt vmcnt(6)" ::: "memory");
    __builtin_amdgcn_s_barrier();

#pragma unroll 2
    for (int kt = 0; kt < 16; ++kt) {
        const int p = kt & 1;
        const int ktA = (kt + 1) & 15;
        const int ktB = (kt + 2) & 15;
        const int pA = ktA & 1;
        bf16x8 a0[2], a1[2];
        // ---- P0
        G1_READA(0, p, a0, a1)
#pragma unroll
        for (int ni = 0; ni < 4; ++ni) {
            const u16* bb = smem + (p * 4 + 2 + bSlotHi) * SLOT + bRd + ni * 1024;
            bfr[ni][0] = *(const bf16x8*)&bb[c0];
            bfr[ni][1] = *(const bf16x8*)&bb[c1];
        }
        stageA(0, ktA, pA * 4);
        __builtin_amdgcn_s_barrier();
        asm volatile("s_waitcnt lgkmcnt(0)" ::: "memory");
        __builtin_amdgcn_sched_barrier(0);
        __builtin_amdgcn_s_setprio(1);
        G1_MFMA(0, a0, a1)
        __builtin_amdgcn_s_setprio(0);
        // ---- P1
        G1_READA(1, p, a0, a1)
        stageA(1, ktA, pA * 4 + 1);
        asm volatile("s_waitcnt vmcnt(8)" ::: "memory");
        __builtin_amdgcn_s_barrier();
        asm volatile("s_waitcnt lgkmcnt(0)" ::: "memory");
        __builtin_amdgcn_sched_barrier(0);
        __builtin_amdgcn_s_setprio(1);
        G1_MFMA(1, a0, a1)
        __builtin_amdgcn_s_setprio(0);
        // ---- P2
        G1_READA(2, p, a0, a1)
        stageB(0, ktB, p * 4 + 2);
        __builtin_amdgcn_s_barrier();
        asm volatile("s_waitcnt lgkmcnt(0)" ::: "memory");
        __builtin_amdgcn_sched_barrier(0);
        __builtin_amdgcn_s_setprio(1);
        G1_MFMA(2, a0, a1)
        __builtin_amdgcn_s_setprio(0);
        // ---- P3
        G1_READA(3, p, a0, a1)
        stageB(1, ktB, p * 4 + 3);
        asm volatile("s_waitcnt vmcnt(6)" ::: "memory");
        __builtin_amdgcn_s_barrier();
        asm volatile("s_waitcnt lgkmcnt(0)" ::: "memory");
        __builtin_amdgcn_sched_barrier(0);
        __builtin_amdgcn_s_setprio(1);
        G1_MFMA(3, a0, a1)
        __builtin_amdgcn_s_setprio(0);
    }
#undef G1_READA
#undef G1_MFMA

    const int crow = (lane >> 4) * 4;
    __syncthreads();   // drain wraparound gload_lds stages; smem reusable (both paths)
    if (bx != 9) {
        // ---- phase 1: Y = gelu(acc+bias) -> smem [256][256] bf16, slot-XOR swizzle
#pragma unroll
        for (int j = 0; j < 8; ++j) {
#pragma unroll
            for (int ni = 0; ni < 4; ++ni) {
                const int col = wc * 64 + ni * 16 + l15;          // block-local k of 2nd gemm
                const float bias = biascat[n0 + col];
#pragma unroll
                for (int r = 0; r < 4; ++r) {
                    const int row = wr * 16 + j * 32 + crow + r;  // block-local token row
                    const float v = gelu_fast(acc[j][ni][r] + bias);
                    smem[row * 256 + ((((col >> 3) ^ (row & 15)) << 3) | (col & 7))] = f2bf(v);
                }
            }
        }
        __syncthreads();
        // ---- phase 2: P = Y @ w2slice; wave owns rows wid*32..+32, full k=256
        f32x4 accP[2][2];
#pragma unroll
        for (int m = 0; m < 2; ++m)
#pragma unroll
            for (int n = 0; n < 2; ++n) accP[m][n] = (f32x4){0.f, 0.f, 0.f, 0.f};
        const int lh16 = lane >> 4;
#pragma unroll
        for (int g = 0; g < 8; ++g) {
            bf16x8 bv[2], av[2];
#pragma unroll
            for (int ni = 0; ni < 2; ++ni)
                bv[ni] = *(const bf16x8*)(w2t + (size_t)(ni * 16 + l15) * K2 + n0 + g * 32 + lh16 * 8);
#pragma unroll
            for (int m = 0; m < 2; ++m) {
                const int row = wid * 32 + m * 16 + l15;
                av[m] = *(const bf16x8*)&smem[row * 256 + (((g * 4 + lh16) ^ l15) << 3)];
            }
#pragma unroll
            for (int m = 0; m < 2; ++m)
#pragma unroll
                for (int ni = 0; ni < 2; ++ni)
                    accP[m][ni] = __builtin_amdgcn_mfma_f32_16x16x32_bf16(av[m], bv[ni], accP[m][ni], 0, 0, 0);
        }
#pragma unroll
        for (int m = 0; m < 2; ++m)
#pragma unroll
            for (int ni = 0; ni < 2; ++ni)
#pragma unroll
                for (int r = 0; r < 4; ++r) {
                    const int row = m0 + wid * 32 + m * 16 + crow + r;
                    Pb[((size_t)row * 9 + bx) * 32 + ni * 16 + l15] = accP[m][ni][r];
                }
    } else {
        // fused router + value head (verified round 10/12)
        for (int i = tid; i < RH_DIM * E_NUM; i += 512) rw2s[i] = rw2[i];
        if (tid < RH_DIM) vws[tid] = vw2[tid];
        if (tid < E_NUM) rb2s[tid] = rb2[tid];
        char* sb = (char*)smem;
#pragma unroll
        for (int j = 0; j < 8; ++j) {
#pragma unroll
            for (int ni = 0; ni < 4; ++ni) {
                const int col = wc * 64 + ni * 16 + l15;
                const float bias = biascat[2304 + col];
#pragma unroll
                for (int r = 0; r < 4; ++r) {
                    const int row = wr * 16 + j * 32 + crow + r;
                    float v = acc[j][ni][r] + bias;
                    v = (col < 128) ? gelu_fast(v) : fmaxf(v, 0.f);
                    *(u16*)(sb + row * 512 + ((col * 2) ^ ((row & 31) << 4))) = f2bf(v);
                }
            }
        }
        __syncthreads();
        if (tid < 256) {
            const int row = tid;
            float lg[E_NUM];
#pragma unroll
            for (int e = 0; e < E_NUM; ++e) lg[e] = rb2s[e];
            const int rx = (row & 31) << 4;
#pragma unroll 4
            for (int s = 0; s < 16; ++s) {
                u16x8 v8 = *(const u16x8*)(sb + row * 512 + ((s << 4) ^ rx));
#pragma unroll
                for (int q = 0; q < 8; ++q) {
                    const float xv = bf2f(v8[q]);
                    const float* wr8 = &rw2s[(s * 8 + q) * E_NUM];
#pragma unroll
                    for (int e = 0; e < E_NUM; ++e) lg[e] = fmaf(xv, wr8[e], lg[e]);
                }
            }
            float mx = lg[0];
#pragma unroll
            for (int e = 1; e < E_NUM; ++e) mx = fmaxf(mx, lg[e]);
            float sm = 0.f;
            float ex[E_NUM];
#pragma unroll
            for (int e = 0; e < E_NUM; ++e) { ex[e] = __expf(lg[e] - mx); sm += ex[e]; }
            const float rs = 1.0f / sm;
#pragma unroll
            for (int e = 0; e < E_NUM; ++e) probs_out[(size_t)(m0 + row) * E_NUM + e] = ex[e] * rs;
        } else {
            const int row = tid - 256;
            const int rx = (row & 31) << 4;
            float pv = 0.f;
#pragma unroll 4
            for (int s = 16; s < 32; ++s) {
                u16x8 v8 = *(const u16x8*)(sb + row * 512 + ((s << 4) ^ rx));
#pragma unroll
                for (int q = 0; q < 8; ++q) pv = fmaf(bf2f(v8[q]), vws[(s - 16) * 8 + q], pv);
            }
            rtg_out[m0 + row] = 1.f / (1.f + __expf(-(pv + vb2[0])));
        }
    }
}

// ---------------- combine: weighted sum of Pbuf + fused residual MLP + final ----------------
// Structure = round-10's verified gemm2 epilogue (E1/E2/E3), with accT/accS
// replaced by Pbuf reads: wgt = sum_e p_e*(P_e + eb2_e); moe = wgt + P_8 + sb2.

__launch_bounds__(256, 3)
__global__ void k_combine(const float* __restrict__ Pb, const float* __restrict__ probs,
                          const float* __restrict__ eb2, const float* __restrict__ sb2,
                          const u16* __restrict__ w1b, const u16* __restrict__ w2b,
                          const float* __restrict__ mb1, const float* __restrict__ mb2,
                          const float* __restrict__ mask, float* __restrict__ out_final) {
    __shared__ float plds[64 * E_NUM];
    __shared__ u16 Am[64 * 40];
    __shared__ u16 rhm[64 * 136];
    __shared__ u16 w1s[32 * 128];
    __shared__ u16 w2s[32 * 136];
    const int tid = threadIdx.x;
    const int wid = tid >> 6;
    const int lane = tid & 63;
    const int m0 = blockIdx.x * 64;
    const int crow = (lane >> 4) * 4;
    const int ccol = lane & 15;

    for (int i = tid; i < 64 * E_NUM; i += 256) plds[i] = probs[(size_t)m0 * E_NUM + i];
    for (int i = tid; i < 4096; i += 256) w1s[i] = w1b[i];
    for (int i = tid; i < 544; i += 256) *(u16x8*)&w2s[i * 8] = *(const u16x8*)&w2b[i * 8];
    __syncthreads();

    // ---- E1: wgt in regs; moe -> Am
    float wgt[2][4];
#pragma unroll
    for (int n = 0; n < 2; ++n) {
        const int aIdx = n * 16 + ccol;
#pragma unroll
        for (int r = 0; r < 4; ++r) {
            const int row = wid * 16 + crow + r;
            const float* pt = Pb + (size_t)(m0 + row) * 288;
            float w = 0.f;
#pragma unroll
            for (int e = 0; e < E_NUM; ++e)
                w = fmaf(plds[row * E_NUM + e], pt[e * 32 + aIdx] + eb2[e * A_DIM + aIdx], w);
            wgt[n][r] = w;
            Am[row * 40 + aIdx] = f2bf(w + pt[256 + aIdx] + sb2[aIdx]);   // moe
        }
    }
    __syncthreads();
    {   // ---- E2: rh[row][j] = gelu(moe_row @ mw1 + mb1)
        const int row = tid >> 2, seg = tid & 3;
        float mrow[32];
#pragma unroll
        for (int a = 0; a < 32; ++a) mrow[a] = bf2f(Am[row * 40 + a]);
#pragma unroll 4
        for (int jj = 0; jj < 32; ++jj) {
            const int j = seg * 32 + jj;
            float s = mb1[j];
#pragma unroll
            for (int a = 0; a < 32; ++a) s = fmaf(mrow[a], bf2f(w1s[a * 128 + j]), s);
            rhm[row * 136 + j] = f2bf(gelu_fast(s));
        }
    }
    __syncthreads();
    // ---- E3: final = wgt + rh @ mw2 + mb2, masked
#pragma unroll
    for (int n = 0; n < 2; ++n) {
        const int aIdx = n * 16 + ccol;
        const float b2 = mb2[aIdx];
#pragma unroll
        for (int r = 0; r < 4; ++r) {
            const int row = wid * 16 + crow + r;
            float s = b2;
#pragma unroll
            for (int jc = 0; jc < 16; ++jc) {
                u16x8 rv = *(const u16x8*)&rhm[row * 136 + jc * 8];
                u16x8 wv = *(const u16x8*)&w2s[aIdx * 136 + jc * 8];
#pragma unroll
                for (int q = 0; q < 8; ++q) s = fmaf(bf2f(rv[q]), bf2f(wv[q]), s);
            }
            const int t = m0 + row;
            out_final[(size_t)t * A_DIM + aIdx] = (wgt[n][r] + s) * mask[t];
        }
    }
}

// ---------------- launch ----------------

extern "C" void kernel_launch(void* const* d_in, const int* in_sizes, int n_in,
                              void* d_out, int out_size, void* d_ws, size_t ws_size,
                              hipStream_t stream) {
    const float* state = (const float*)d_in[0];
    const float* base  = (const float*)d_in[1];
    const float* mask  = (const float*)d_in[2];
    const float* sw1 = (const float*)d_in[3];
    const float* sb1 = (const float*)d_in[4];
    const float* sw2 = (const float*)d_in[5];
    const float* sb2 = (const float*)d_in[6];
    const float* ew1 = (const float*)d_in[7];
    const float* eb1 = (const float*)d_in[8];
    const float* ew2 = (const float*)d_in[9];
    const float* eb2 = (const float*)d_in[10];
    const float* rw1 = (const float*)d_in[11];
    const float* rb1 = (const float*)d_in[12];
    const float* rw2 = (const float*)d_in[13];
    const float* rb2 = (const float*)d_in[14];
    const float* mw1 = (const float*)d_in[15];
    const float* mb1 = (const float*)d_in[16];
    const float* mw2 = (const float*)d_in[17];
    const float* mb2 = (const float*)d_in[18];
    const float* vw1 = (const float*)d_in[19];
    const float* vb1 = (const float*)d_in[20];
    const float* vw2 = (const float*)d_in[21];
    const float* vb2 = (const float*)d_in[22];

    float* out_final = (float*)d_out;                 // [32768][32]
    float* out_cand  = out_final + 1048576;           // [32768][8][32]
    float* out_probs = out_final + 9437184;           // [32768][8]
    float* out_rtg   = out_final + 9699328;           // [32768]

    auto al = [](size_t b) { return (b + 255) & ~(size_t)255; };
    auto need = [&](size_t T) {
        return al((size_t)NBIG * H_DIM * 2) + al((size_t)A_DIM * K2 * 2) + al((size_t)NBIG * 4)
             + al((size_t)4096 * 2) + al((size_t)4352 * 2)
             + al(T * H_DIM * 2) + al(T * 9 * A_DIM * 4);
    };
    size_t Tc = 8192;
    if (need(32768) <= ws_size)      Tc = 32768;
    else if (need(16384) <= ws_size) Tc = 16384;
    const int nchunk = (int)(T_TOT / Tc);

    char* ws = (char*)d_ws;
    size_t off = 0;
    auto take = [&](size_t b) { char* p = ws + off; off += (b + 255) & ~(size_t)255; return p; };
    u16*   wbf   = (u16*)take((size_t)NBIG * H_DIM * 2);
    u16*   w2t   = (u16*)take((size_t)A_DIM * K2 * 2);
    float* bias  = (float*)take((size_t)NBIG * 4);
    u16*   w1b   = (u16*)take((size_t)4096 * 2);
    u16*   w2b   = (u16*)take((size_t)4352 * 2);
    u16*   xb    = (u16*)take(Tc * H_DIM * 2);
    float* Pb    = (float*)take(Tc * 9 * A_DIM * 4);
    (void)in_sizes; (void)n_in; (void)out_size;

    const int nconv4 = (Tc == 32768) ? (T_TOT * H_DIM / 4) : 0;
    const int ntot = SB_CND + nconv4;
    k_packwt<<<640, 256, 0, stream>>>(ew1, sw1, rw1, vw1, wbf);
    k_setup<<<(ntot + 255) / 256, 256, 0, stream>>>(
        eb1, sb1, rb1, vb1, ew2, sw2, mw1, mw2,
        base, state, bias, w2t, w1b, w2b, out_cand, xb, nconv4);

    for (int c = 0; c < nchunk; ++c) {
        const size_t tb = (size_t)c * Tc;
        if (nconv4 == 0)
            k_convert_x<<<(int)(Tc * H_DIM / 4 / 256), 256, 0, stream>>>(state + tb * H_DIM, xb, (int)(Tc * H_DIM / 4));
        k_gemm1<<<10 * (int)(Tc / 256), 512, 0, stream>>>(xb, wbf, bias, w2t, Pb,
                                                          rw2, rb2, vw2, vb2,
                                                          out_probs + tb * E_NUM, out_rtg + tb);
        k_combine<<<(int)(Tc / 64), 256, 0, stream>>>(Pb, out_probs + tb * E_NUM, eb2, sb2,
                                                      w1b, w2b, mb1, mb2, mask + tb, out_final + tb * A_DIM);
    }
}

// Round 14
// 251.256 us; speedup vs baseline: 1.8472x; 1.0937x over previous
//
#include <hip/hip_runtime.h>
#include <stdint.h>

// Problem dims
#define T_TOT 32768   // B*S
#define H_DIM 1024
#define A_DIM 32
#define E_NUM 8
#define ED_DIM 256
#define RH_DIM 128
#define NBIG 2560     // 8*256 experts + 256 shared + 128 router + 128 value
#define K2 2304       // 8*256 + 256 (expert+shared h1 -> action)

typedef float f32x4 __attribute__((ext_vector_type(4)));
typedef short bf16x8 __attribute__((ext_vector_type(8)));
typedef unsigned short u16;
typedef u16 u16x8 __attribute__((ext_vector_type(8)));

typedef uint32_t __attribute__((address_space(1))) as1_u32;
typedef uint32_t __attribute__((address_space(3))) as3_u32;

__device__ __forceinline__ u16 f2bf(float f) {
    union { float f; uint32_t u; } v; v.f = f;
    return (u16)((v.u + 0x7FFFu + ((v.u >> 16) & 1u)) >> 16);  // RNE
}
__device__ __forceinline__ float bf2f(u16 h) {
    union { uint32_t u; float f; } v; v.u = ((uint32_t)h) << 16;
    return v.f;
}
// tanh-form GELU: x * sigmoid(1.5957691*x*(1+0.044715 x^2)).
__device__ __forceinline__ float gelu_fast(float x) {
    const float x2 = x * x;
    const float s = x * fmaf(0.07135481627f, x2, 1.5957691216f);  // 2z
    const float e = __expf(-s);
    return x * __builtin_amdgcn_rcpf(1.0f + e);
}
__device__ __forceinline__ void gload_lds16(const void* g, void* lds) {
    __builtin_amdgcn_global_load_lds((const as1_u32*)(uintptr_t)g,
                                     (as3_u32*)(uintptr_t)lds, 16, 0, 0);
}

// ---------------- fused setup: packwt (blocks 0..639) | flat setup (rest) ----------------
// packwt: 64x64 LDS transpose of Wbig^T, both sides coalesced (verified r12/13).
// flat part (thread-slot ranges): w2t | w1b | w2b(pad 136) | biascat |
//   cand x4 (float4 in/out) | state->bf16 x8 (2x float4 read, 16B store).

#define PW_BLKS 640
#define C0 (A_DIM * K2)          // w2t end (73728)
#define C1 (C0 + 4096)           // w1b end
#define C2 (C1 + 4352)           // w2b end
#define C3 (C2 + NBIG)           // bias end
#define C4 (C3 + T_TOT * E_NUM * A_DIM / 4)   // cand end (x4 vectorized)

__global__ void k_setup(const float* __restrict__ ew1, const float* __restrict__ sw1,
                        const float* __restrict__ rw1, const float* __restrict__ vw1,
                        const float* __restrict__ eb1, const float* __restrict__ sb1,
                        const float* __restrict__ rb1, const float* __restrict__ vb1,
                        const float* __restrict__ ew2, const float* __restrict__ sw2,
                        const float* __restrict__ mw1, const float* __restrict__ mw2,
                        const float* __restrict__ base, const float* __restrict__ state,
                        u16* __restrict__ wbf, float* __restrict__ biascat,
                        u16* __restrict__ w2t, u16* __restrict__ w1b, u16* __restrict__ w2b,
                        float* __restrict__ cand_out, u16* __restrict__ xb, int nconv8) {
    __shared__ float t[64][65];
    if (blockIdx.x < PW_BLKS) {
        // ---- packwt: transpose Wbig into wbf [NBIG][1024] bf16
        const int nt = blockIdx.x >> 4, kt = blockIdx.x & 15;
        const int n0 = nt * 64, k0 = kt * 64;
        const int tx = threadIdx.x & 63, ty = threadIdx.x >> 6;
#pragma unroll 4
        for (int it = 0; it < 16; ++it) {
            const int k = k0 + ty + it * 4;
            const int n = n0 + tx;
            float v;
            if (n0 < 2048)      v = ew1[(size_t)((n0 >> 8) * H_DIM + k) * ED_DIM + (n & 255)];
            else if (n0 < 2304) v = sw1[(size_t)k * ED_DIM + (n - 2048)];
            else if (n0 < 2432) v = rw1[(size_t)k * RH_DIM + (n - 2304)];
            else                v = vw1[(size_t)k * RH_DIM + (n - 2432)];
            t[ty + it * 4][tx] = v;
        }
        __syncthreads();
#pragma unroll 4
        for (int it = 0; it < 16; ++it) {
            const int nl = ty + it * 4;
            wbf[(size_t)(n0 + nl) * H_DIM + k0 + tx] = f2bf(t[tx][nl]);
        }
        return;
    }
    const int i = (blockIdx.x - PW_BLKS) * 256 + threadIdx.x;
    if (i < C0) {
        int a = i / K2, d = i - a * K2;
        float v = (d < 2048) ? ew2[(size_t)d * A_DIM + a] : sw2[(size_t)(d - 2048) * A_DIM + a];
        w2t[i] = f2bf(v);
    } else if (i < C1) {
        int q = i - C0;                          // mw1 [32][128] straight
        w1b[q] = f2bf(mw1[q]);
    } else if (i < C2) {
        int q = i - C1;                          // w2b[c][j] padded [32][136], = mw2[j][c]
        int c = q / 136, j = q - c * 136;
        w2b[q] = (j < RH_DIM) ? f2bf(mw2[(size_t)j * A_DIM + c]) : (u16)0;
    } else if (i < C3) {
        int n = i - C2;
        float b;
        if (n < 2048)      b = eb1[(n >> 8) * ED_DIM + (n & 255)];
        else if (n < 2304) b = sb1[n - 2048];
        else if (n < 2432) b = rb1[n - 2304];
        else               b = vb1[n - 2432];
        biascat[n] = b;
    } else if (i < C4) {
        // cand, 4 consecutive a per thread: g = t4*4 -> (tt, e, a0), 4 | 32
        const int t4 = i - C3;
        const int g = t4 * 4;
        const int e = (g >> 5) & 7;
        const float scl = 0.8f + 0.4f * (float)e / 7.0f;
        const int bidx = ((g >> 8) * A_DIM + (g & 31)) >> 2;
        float4 v = ((const float4*)base)[bidx];
        v.x *= scl; v.y *= scl; v.z *= scl; v.w *= scl;
        ((float4*)cand_out)[t4] = v;
    } else if (i < C4 + nconv8) {
        // state f32 -> bf16, 8 per thread (16B store)
        const int q = i - C4;
        float4 v0 = ((const float4*)state)[q * 2];
        float4 v1 = ((const float4*)state)[q * 2 + 1];
        u16x8 o;
        o[0] = f2bf(v0.x); o[1] = f2bf(v0.y); o[2] = f2bf(v0.z); o[3] = f2bf(v0.w);
        o[4] = f2bf(v1.x); o[5] = f2bf(v1.y); o[6] = f2bf(v1.z); o[7] = f2bf(v1.w);
        ((u16x8*)xb)[q] = o;
    }
}

// fallback converter for chunked mode
__global__ void k_convert_x(const float* __restrict__ x, u16* __restrict__ xb, int n4) {
    int i = blockIdx.x * blockDim.x + threadIdx.x;
    if (i >= n4) return;
    float4 v = ((const float4*)x)[i];
    ushort4 o;
    o.x = f2bf(v.x); o.y = f2bf(v.y); o.z = f2bf(v.z); o.w = f2bf(v.w);
    ((ushort4*)xb)[i] = o;
}

// ---------------- GEMM1: X[Tx1024] @ Wbig, fused second GEMM -> Pbuf(bf16) + fused router/value ----------------
// Main loop: m201-style 8-phase ring, verbatim (verified rounds 7-13).
// Epilogue bx<9: Y=gelu(acc+bias) -> smem [256][256] bf16 (slot-XOR involution),
// wave-private P = Y @ w2t-slice via 32 MFMAs, store bf16 partials to Pb.
// Epilogue bx==9: fused router+value (verified rounds 10-13).

#define SLOT 8192   // u16 per 16KB slot (128 rows x 64)

__launch_bounds__(512, 2)
__global__ void k_gemm1(const u16* __restrict__ xb, const u16* __restrict__ wbf,
                        const float* __restrict__ biascat, const u16* __restrict__ w2t,
                        u16* __restrict__ Pb,
                        const float* __restrict__ rw2, const float* __restrict__ rb2,
                        const float* __restrict__ vw2, const float* __restrict__ vb2,
                        float* __restrict__ probs_out, float* __restrict__ rtg_out) {
    __shared__ u16 smem[8 * SLOT];   // 128 KB; epilogue: Y [256][256] bf16
    __shared__ float rw2s[RH_DIM * E_NUM];
    __shared__ float vws[RH_DIM];
    __shared__ float rb2s[E_NUM];
    const int tid = threadIdx.x;
    const int wid = tid >> 6;
    const int lane = tid & 63;
    const int lin = blockIdx.x;
    const int swz = (lin & 7) * ((int)gridDim.x >> 3) + (lin >> 3);
    const int bx = swz % 10;            // n-tile (NBIG/256 = 10)
    const int by = swz / 10;            // m-tile
    const int m0 = by * 256, n0 = bx * 256;
    const int wr = wid >> 2;
    const int wc = wid & 3;
    const int srow = tid >> 3;
    const int cs = 8 * ((tid & 7) ^ (srow & 7));
    const int l15 = lane & 15;
    const int rsw = (lane & 7) * 8;
    const int lh8 = (lane >> 4) * 8;
    const int c0 = lh8 ^ rsw;
    const int c1 = (32 + lh8) ^ rsw;
    const int aRd = (wr * 16 + l15) * 64;
    const int bRd = ((wc & 1) * 64 + l15) * 64;
    const int bSlotHi = wc >> 1;

    f32x4 acc[8][4];
#pragma unroll
    for (int j = 0; j < 8; ++j)
#pragma unroll
        for (int n = 0; n < 4; ++n) acc[j][n] = (f32x4){0.f, 0.f, 0.f, 0.f};

    auto stageA = [&](int h, int kt, int s) {
        const u16* src = xb + (size_t)(m0 + h * 128 + srow) * H_DIM + kt * 64 + cs;
        u16* dst = smem + s * SLOT + wid * 512;
        gload_lds16(src, dst);
        gload_lds16(src + (size_t)64 * H_DIM, dst + 4096);
    };
    auto stageB = [&](int h, int kt, int s) {
        const u16* src = wbf + (size_t)(n0 + h * 128 + srow) * H_DIM + kt * 64 + cs;
        u16* dst = smem + s * SLOT + wid * 512;
        gload_lds16(src, dst);
        gload_lds16(src + (size_t)64 * H_DIM, dst + 4096);
    };

    bf16x8 bfr[4][2];

#define G1_READA(q, P, A0, A1)                                                    \
    {                                                                             \
        const u16* ab0 = smem + ((P) * 4 + ((q) >> 1)) * SLOT + aRd + (((2*(q)) & 3) * 2048);     \
        const u16* ab1 = smem + ((P) * 4 + ((q) >> 1)) * SLOT + aRd + (((2*(q)+1) & 3) * 2048);   \
        A0[0] = *(const bf16x8*)&ab0[c0]; A0[1] = *(const bf16x8*)&ab0[c1];       \
        A1[0] = *(const bf16x8*)&ab1[c0]; A1[1] = *(const bf16x8*)&ab1[c1];       \
    }

#define G1_MFMA(q, A0, A1)                                                        \
    _Pragma("unroll")                                                             \
    for (int ni = 0; ni < 4; ++ni) {                                              \
        acc[2*(q)][ni]   = __builtin_amdgcn_mfma_f32_16x16x32_bf16(A0[0], bfr[ni][0], acc[2*(q)][ni], 0, 0, 0);   \
        acc[2*(q)][ni]   = __builtin_amdgcn_mfma_f32_16x16x32_bf16(A0[1], bfr[ni][1], acc[2*(q)][ni], 0, 0, 0);   \
        acc[2*(q)+1][ni] = __builtin_amdgcn_mfma_f32_16x16x32_bf16(A1[0], bfr[ni][0], acc[2*(q)+1][ni], 0, 0, 0); \
        acc[2*(q)+1][ni] = __builtin_amdgcn_mfma_f32_16x16x32_bf16(A1[1], bfr[ni][1], acc[2*(q)+1][ni], 0, 0, 0); \
    }

    stageB(0, 0, 2); stageB(1, 0, 3);
    stageA(0, 0, 0); stageA(1, 0, 1);
    stageB(0, 1, 6); stageB(1, 1, 7);
    asm volatile("s_waitcnt vmcnt(6)" ::: "memory");
    __builtin_amdgcn_s_barrier();

#pragma unroll 2
    for (int kt = 0; kt < 16; ++kt) {
        const int p = kt & 1;
        const int ktA = (kt + 1) & 15;
        const int ktB = (kt + 2) & 15;
        const int pA = ktA & 1;
        bf16x8 a0[2], a1[2];
        // ---- P0
        G1_READA(0, p, a0, a1)
#pragma unroll
        for (int ni = 0; ni < 4; ++ni) {
            const u16* bb = smem + (p * 4 + 2 + bSlotHi) * SLOT + bRd + ni * 1024;
            bfr[ni][0] = *(const bf16x8*)&bb[c0];
            bfr[ni][1] = *(const bf16x8*)&bb[c1];
        }
        stageA(0, ktA, pA * 4);
        __builtin_amdgcn_s_barrier();
        asm volatile("s_waitcnt lgkmcnt(0)" ::: "memory");
        __builtin_amdgcn_sched_barrier(0);
        __builtin_amdgcn_s_setprio(1);
        G1_MFMA(0, a0, a1)
        __builtin_amdgcn_s_setprio(0);
        // ---- P1
        G1_READA(1, p, a0, a1)
        stageA(1, ktA, pA * 4 + 1);
        asm volatile("s_waitcnt vmcnt(8)" ::: "memory");
        __builtin_amdgcn_s_barrier();
        asm volatile("s_waitcnt lgkmcnt(0)" ::: "memory");
        __builtin_amdgcn_sched_barrier(0);
        __builtin_amdgcn_s_setprio(1);
        G1_MFMA(1, a0, a1)
        __builtin_amdgcn_s_setprio(0);
        // ---- P2
        G1_READA(2, p, a0, a1)
        stageB(0, ktB, p * 4 + 2);
        __builtin_amdgcn_s_barrier();
        asm volatile("s_waitcnt lgkmcnt(0)" ::: "memory");
        __builtin_amdgcn_sched_barrier(0);
        __builtin_amdgcn_s_setprio(1);
        G1_MFMA(2, a0, a1)
        __builtin_amdgcn_s_setprio(0);
        // ---- P3
        G1_READA(3, p, a0, a1)
        stageB(1, ktB, p * 4 + 3);
        asm volatile("s_waitcnt vmcnt(6)" ::: "memory");
        __builtin_amdgcn_s_barrier();
        asm volatile("s_waitcnt lgkmcnt(0)" ::: "memory");
        __builtin_amdgcn_sched_barrier(0);
        __builtin_amdgcn_s_setprio(1);
        G1_MFMA(3, a0, a1)
        __builtin_amdgcn_s_setprio(0);
    }
#undef G1_READA
#undef G1_MFMA

    const int crow = (lane >> 4) * 4;
    __syncthreads();   // drain wraparound gload_lds stages; smem reusable (both paths)
    if (bx != 9) {
        // ---- phase 1: Y = gelu(acc+bias) -> smem [256][256] bf16, slot-XOR swizzle
#pragma unroll
        for (int j = 0; j < 8; ++j) {
#pragma unroll
            for (int ni = 0; ni < 4; ++ni) {
                const int col = wc * 64 + ni * 16 + l15;          // block-local k of 2nd gemm
                const float bias = biascat[n0 + col];
#pragma unroll
                for (int r = 0; r < 4; ++r) {
                    const int row = wr * 16 + j * 32 + crow + r;  // block-local token row
                    const float v = gelu_fast(acc[j][ni][r] + bias);
                    smem[row * 256 + ((((col >> 3) ^ (row & 15)) << 3) | (col & 7))] = f2bf(v);
                }
            }
        }
        __syncthreads();
        // ---- phase 2: P = Y @ w2slice; wave owns rows wid*32..+32, full k=256
        f32x4 accP[2][2];
#pragma unroll
        for (int m = 0; m < 2; ++m)
#pragma unroll
            for (int n = 0; n < 2; ++n) accP[m][n] = (f32x4){0.f, 0.f, 0.f, 0.f};
        const int lh16 = lane >> 4;
#pragma unroll
        for (int g = 0; g < 8; ++g) {
            bf16x8 bv[2], av[2];
#pragma unroll
            for (int ni = 0; ni < 2; ++ni)
                bv[ni] = *(const bf16x8*)(w2t + (size_t)(ni * 16 + l15) * K2 + n0 + g * 32 + lh16 * 8);
#pragma unroll
            for (int m = 0; m < 2; ++m) {
                const int row = wid * 32 + m * 16 + l15;
                av[m] = *(const bf16x8*)&smem[row * 256 + (((g * 4 + lh16) ^ l15) << 3)];
            }
#pragma unroll
            for (int m = 0; m < 2; ++m)
#pragma unroll
                for (int ni = 0; ni < 2; ++ni)
                    accP[m][ni] = __builtin_amdgcn_mfma_f32_16x16x32_bf16(av[m], bv[ni], accP[m][ni], 0, 0, 0);
        }
#pragma unroll
        for (int m = 0; m < 2; ++m)
#pragma unroll
            for (int ni = 0; ni < 2; ++ni)
#pragma unroll
                for (int r = 0; r < 4; ++r) {
                    const int row = m0 + wid * 32 + m * 16 + crow + r;
                    Pb[((size_t)row * 9 + bx) * 32 + ni * 16 + l15] = f2bf(accP[m][ni][r]);
                }
    } else {
        // fused router + value head (verified rounds 10-13)
        for (int i = tid; i < RH_DIM * E_NUM; i += 512) rw2s[i] = rw2[i];
        if (tid < RH_DIM) vws[tid] = vw2[tid];
        if (tid < E_NUM) rb2s[tid] = rb2[tid];
        char* sb = (char*)smem;
#pragma unroll
        for (int j = 0; j < 8; ++j) {
#pragma unroll
            for (int ni = 0; ni < 4; ++ni) {
                const int col = wc * 64 + ni * 16 + l15;
                const float bias = biascat[2304 + col];
#pragma unroll
                for (int r = 0; r < 4; ++r) {
                    const int row = wr * 16 + j * 32 + crow + r;
                    float v = acc[j][ni][r] + bias;
                    v = (col < 128) ? gelu_fast(v) : fmaxf(v, 0.f);
                    *(u16*)(sb + row * 512 + ((col * 2) ^ ((row & 31) << 4))) = f2bf(v);
                }
            }
        }
        __syncthreads();
        if (tid < 256) {
            const int row = tid;
            float lg[E_NUM];
#pragma unroll
            for (int e = 0; e < E_NUM; ++e) lg[e] = rb2s[e];
            const int rx = (row & 31) << 4;
#pragma unroll 4
            for (int s = 0; s < 16; ++s) {
                u16x8 v8 = *(const u16x8*)(sb + row * 512 + ((s << 4) ^ rx));
#pragma unroll
                for (int q = 0; q < 8; ++q) {
                    const float xv = bf2f(v8[q]);
                    const float* wr8 = &rw2s[(s * 8 + q) * E_NUM];
#pragma unroll
                    for (int e = 0; e < E_NUM; ++e) lg[e] = fmaf(xv, wr8[e], lg[e]);
                }
            }
            float mx = lg[0];
#pragma unroll
            for (int e = 1; e < E_NUM; ++e) mx = fmaxf(mx, lg[e]);
            float sm = 0.f;
            float ex[E_NUM];
#pragma unroll
            for (int e = 0; e < E_NUM; ++e) { ex[e] = __expf(lg[e] - mx); sm += ex[e]; }
            const float rs = 1.0f / sm;
#pragma unroll
            for (int e = 0; e < E_NUM; ++e) probs_out[(size_t)(m0 + row) * E_NUM + e] = ex[e] * rs;
        } else {
            const int row = tid - 256;
            const int rx = (row & 31) << 4;
            float pv = 0.f;
#pragma unroll 4
            for (int s = 16; s < 32; ++s) {
                u16x8 v8 = *(const u16x8*)(sb + row * 512 + ((s << 4) ^ rx));
#pragma unroll
                for (int q = 0; q < 8; ++q) pv = fmaf(bf2f(v8[q]), vws[(s - 16) * 8 + q], pv);
            }
            rtg_out[m0 + row] = 1.f / (1.f + __expf(-(pv + vb2[0])));
        }
    }
}

// ---------------- combine: weighted sum of Pbuf(bf16) + fused residual MLP + final ----------------
// Structure = verified round-13 combine; Pb now bf16.

__launch_bounds__(256, 3)
__global__ void k_combine(const u16* __restrict__ Pb, const float* __restrict__ probs,
                          const float* __restrict__ eb2, const float* __restrict__ sb2,
                          const u16* __restrict__ w1b, const u16* __restrict__ w2b,
                          const float* __restrict__ mb1, const float* __restrict__ mb2,
                          const float* __restrict__ mask, float* __restrict__ out_final) {
    __shared__ float plds[64 * E_NUM];
    __shared__ u16 Am[64 * 40];
    __shared__ u16 rhm[64 * 136];
    __shared__ u16 w1s[32 * 128];
    __shared__ u16 w2s[32 * 136];
    const int tid = threadIdx.x;
    const int wid = tid >> 6;
    const int lane = tid & 63;
    const int m0 = blockIdx.x * 64;
    const int crow = (lane >> 4) * 4;
    const int ccol = lane & 15;

    for (int i = tid; i < 64 * E_NUM; i += 256) plds[i] = probs[(size_t)m0 * E_NUM + i];
    for (int i = tid; i < 4096; i += 256) w1s[i] = w1b[i];
    for (int i = tid; i < 544; i += 256) *(u16x8*)&w2s[i * 8] = *(const u16x8*)&w2b[i * 8];
    __syncthreads();

    // ---- E1: wgt in regs; moe -> Am
    float wgt[2][4];
#pragma unroll
    for (int n = 0; n < 2; ++n) {
        const int aIdx = n * 16 + ccol;
#pragma unroll
        for (int r = 0; r < 4; ++r) {
            const int row = wid * 16 + crow + r;
            const u16* pt = Pb + (size_t)(m0 + row) * 288;
            float w = 0.f;
#pragma unroll
            for (int e = 0; e < E_NUM; ++e)
                w = fmaf(plds[row * E_NUM + e], bf2f(pt[e * 32 + aIdx]) + eb2[e * A_DIM + aIdx], w);
            wgt[n][r] = w;
            Am[row * 40 + aIdx] = f2bf(w + bf2f(pt[256 + aIdx]) + sb2[aIdx]);   // moe
        }
    }
    __syncthreads();
    {   // ---- E2: rh[row][j] = gelu(moe_row @ mw1 + mb1)
        const int row = tid >> 2, seg = tid & 3;
        float mrow[32];
#pragma unroll
        for (int a = 0; a < 32; ++a) mrow[a] = bf2f(Am[row * 40 + a]);
#pragma unroll 4
        for (int jj = 0; jj < 32; ++jj) {
            const int j = seg * 32 + jj;
            float s = mb1[j];
#pragma unroll
            for (int a = 0; a < 32; ++a) s = fmaf(mrow[a], bf2f(w1s[a * 128 + j]), s);
            rhm[row * 136 + j] = f2bf(gelu_fast(s));
        }
    }
    __syncthreads();
    // ---- E3: final = wgt + rh @ mw2 + mb2, masked
#pragma unroll
    for (int n = 0; n < 2; ++n) {
        const int aIdx = n * 16 + ccol;
        const float b2 = mb2[aIdx];
#pragma unroll
        for (int r = 0; r < 4; ++r) {
            const int row = wid * 16 + crow + r;
            float s = b2;
#pragma unroll
            for (int jc = 0; jc < 16; ++jc) {
                u16x8 rv = *(const u16x8*)&rhm[row * 136 + jc * 8];
                u16x8 wv = *(const u16x8*)&w2s[aIdx * 136 + jc * 8];
#pragma unroll
                for (int q = 0; q < 8; ++q) s = fmaf(bf2f(rv[q]), bf2f(wv[q]), s);
            }
            const int t = m0 + row;
            out_final[(size_t)t * A_DIM + aIdx] = (wgt[n][r] + s) * mask[t];
        }
    }
}

// ---------------- launch ----------------

extern "C" void kernel_launch(void* const* d_in, const int* in_sizes, int n_in,
                              void* d_out, int out_size, void* d_ws, size_t ws_size,
                              hipStream_t stream) {
    const float* state = (const float*)d_in[0];
    const float* base  = (const float*)d_in[1];
    const float* mask  = (const float*)d_in[2];
    const float* sw1 = (const float*)d_in[3];
    const float* sb1 = (const float*)d_in[4];
    const float* sw2 = (const float*)d_in[5];
    const float* sb2 = (const float*)d_in[6];
    const float* ew1 = (const float*)d_in[7];
    const float* eb1 = (const float*)d_in[8];
    const float* ew2 = (const float*)d_in[9];
    const float* eb2 = (const float*)d_in[10];
    const float* rw1 = (const float*)d_in[11];
    const float* rb1 = (const float*)d_in[12];
    const float* rw2 = (const float*)d_in[13];
    const float* rb2 = (const float*)d_in[14];
    const float* mw1 = (const float*)d_in[15];
    const float* mb1 = (const float*)d_in[16];
    const float* mw2 = (const float*)d_in[17];
    const float* mb2 = (const float*)d_in[18];
    const float* vw1 = (const float*)d_in[19];
    const float* vb1 = (const float*)d_in[20];
    const float* vw2 = (const float*)d_in[21];
    const float* vb2 = (const float*)d_in[22];

    float* out_final = (float*)d_out;                 // [32768][32]
    float* out_cand  = out_final + 1048576;           // [32768][8][32]
    float* out_probs = out_final + 9437184;           // [32768][8]
    float* out_rtg   = out_final + 9699328;           // [32768]

    auto al = [](size_t b) { return (b + 255) & ~(size_t)255; };
    auto need = [&](size_t T) {
        return al((size_t)NBIG * H_DIM * 2) + al((size_t)A_DIM * K2 * 2) + al((size_t)NBIG * 4)
             + al((size_t)4096 * 2) + al((size_t)4352 * 2)
             + al(T * H_DIM * 2) + al(T * 9 * A_DIM * 2);
    };
    size_t Tc = 8192;
    if (need(32768) <= ws_size)      Tc = 32768;
    else if (need(16384) <= ws_size) Tc = 16384;
    const int nchunk = (int)(T_TOT / Tc);

    char* ws = (char*)d_ws;
    size_t off = 0;
    auto take = [&](size_t b) { char* p = ws + off; off += (b + 255) & ~(size_t)255; return p; };
    u16*   wbf   = (u16*)take((size_t)NBIG * H_DIM * 2);
    u16*   w2t   = (u16*)take((size_t)A_DIM * K2 * 2);
    float* bias  = (float*)take((size_t)NBIG * 4);
    u16*   w1b   = (u16*)take((size_t)4096 * 2);
    u16*   w2b   = (u16*)take((size_t)4352 * 2);
    u16*   xb    = (u16*)take(Tc * H_DIM * 2);
    u16*   Pb    = (u16*)take(Tc * 9 * A_DIM * 2);
    (void)in_sizes; (void)n_in; (void)out_size;

    const int nconv8 = (Tc == 32768) ? (T_TOT * H_DIM / 8) : 0;
    const int flat_blocks = (C4 + nconv8 + 255) / 256;
    k_setup<<<PW_BLKS + flat_blocks, 256, 0, stream>>>(
        ew1, sw1, rw1, vw1, eb1, sb1, rb1, vb1, ew2, sw2, mw1, mw2,
        base, state, wbf, bias, w2t, w1b, w2b, out_cand, xb, nconv8);

    for (int c = 0; c < nchunk; ++c) {
        const size_t tb = (size_t)c * Tc;
        if (nconv8 == 0)
            k_convert_x<<<(int)(Tc * H_DIM / 4 / 256), 256, 0, stream>>>(state + tb * H_DIM, xb, (int)(Tc * H_DIM / 4));
        k_gemm1<<<10 * (int)(Tc / 256), 512, 0, stream>>>(xb, wbf, bias, w2t, Pb,
                                                          rw2, rb2, vw2, vb2,
                                                          out_probs + tb * E_NUM, out_rtg + tb);
        k_combine<<<(int)(Tc / 64), 256, 0, stream>>>(Pb, out_probs + tb * E_NUM, eb2, sb2,
                                                      w1b, w2b, mb1, mb2, mask + tb, out_final + tb * A_DIM);
    }
}